// Round 15
// baseline (297.592 us; speedup 1.0000x reference)
//
#include <hip/hip_runtime.h>
#include <hip/hip_bf16.h>
#include <cstdint>

typedef __attribute__((ext_vector_type(8))) __bf16 bf16x8;
typedef __attribute__((ext_vector_type(8))) unsigned short u16x8;
typedef __attribute__((ext_vector_type(4))) float f32x4;

#define QKSTRIDE 640
#define QKROW 1280
#define VTPAD 528

static __device__ __forceinline__ unsigned short f2bf(float f) {
  __hip_bfloat16 h = __float2bfloat16(f);
  return *reinterpret_cast<unsigned short*>(&h);
}
static __device__ __forceinline__ float bf2f(unsigned short u) {
  union { unsigned v; float f; } c; c.v = ((unsigned)u) << 16; return c.f;
}
static __device__ __forceinline__ unsigned pack2bf(float a, float b) {
  return (unsigned)f2bf(a) | ((unsigned)f2bf(b) << 16);
}

static __device__ __forceinline__ void gload_lds16(const void* g, void* lds) {
  __builtin_amdgcn_global_load_lds(
      (const __attribute__((address_space(1))) unsigned int*)g,
      (__attribute__((address_space(3))) unsigned int*)lds, 16, 0, 0);
}

// ---------------- prep: head dims, loss, maps, split-K schedule (small=64, big=128 blocks/set) ----------------
__global__ void prep_kernel(const float* __restrict__ logits, int* __restrict__ hdr,
                            int* __restrict__ cmap, int* __restrict__ sched,
                            float* __restrict__ loss_out) {
  __shared__ int sh_starts[8], sh_astarts[8];
  __shared__ int sh_ax[24], sh_apos[24], sh_ah[24], sh_ab[24], sh_nb[24];
  const int tid = threadIdx.x;
  if (blockIdx.x != 0) return;

  if (tid == 0) {
    float l[6]; float mx = -1e30f;
    for (int i = 0; i < 6; ++i) { l[i] = logits[i]; mx = fmaxf(mx, l[i]); }
    float e[6]; float s = 0.f;
    for (int i = 0; i < 6; ++i) { e[i] = expf(l[i] - mx); s += e[i]; }
    float hdf[6]; float sumh = 0.f;
    for (int i = 0; i < 6; ++i) { hdf[i] = 8.0f + (e[i] / s) * 464.0f; sumh += hdf[i]; }
    int hdi[6]; float res[6]; int isum = 0;
    for (int i = 0; i < 6; ++i) {
      float fl = floorf(hdf[i]);
      hdi[i] = (int)fl; res[i] = hdf[i] - fl; isum += hdi[i];
    }
    int diff = 512 - isum;
    bool used[6] = {false, false, false, false, false, false};
    if (diff > 0) {
      for (int t = 0; t < diff; ++t) {
        int best = -1; float bv = -1e30f;
        for (int i = 0; i < 6; ++i) if (!used[i] && res[i] > bv) { bv = res[i]; best = i; }
        used[best] = true; hdi[best] += 1;
      }
    } else if (diff < 0) {
      for (int t = 0; t < -diff; ++t) {
        int best = -1; float bv = 1e30f;
        for (int i = 0; i < 6; ++i) if (!used[i] && res[i] < bv) { bv = res[i]; best = i; }
        used[best] = true; hdi[best] -= 1;
      }
    }
    { int st = 0, ast = 0;
      for (int i = 0; i < 6; ++i) {
        sh_starts[i] = st; sh_astarts[i] = ast;
        hdr[i] = hdi[i]; hdr[8 + i] = st; hdr[16 + i] = ast;
        st += hdi[i]; ast += (hdi[i] + 7) & ~7;
      }
      sh_starts[6] = st; sh_starts[7] = st;
    }
    // LPT: per-set block count 64 (nc<=4) / 128 (nc>=5); 8 XCD bins cap 320
    int csth[6], nbh6[6];
    for (int i = 0; i < 6; ++i) {
      int ncl = (hdi[i] + 31) / 32;
      int ntl = (hdi[i] + 15) / 16;
      csth[i] = 4 * ncl + 2 * ntl + 8;
      nbh6[i] = (ncl <= 4) ? 64 : 128;
    }
    int ord[6] = {0, 1, 2, 3, 4, 5};
    for (int a = 0; a < 6; ++a)
      for (int c = a + 1; c < 6; ++c)
        if (csth[ord[c]] > csth[ord[a]]) { int t = ord[a]; ord[a] = ord[c]; ord[c] = t; }
    int binload[8], bincnt[8];
    for (int x = 0; x < 8; ++x) { binload[x] = 0; bincnt[x] = 0; }
    int na = 0;
    for (int a = 0; a < 6; ++a) {
      const int hh = ord[a];
      const int nb = nbh6[hh];
      for (int bb = 0; bb < 4; ++bb) {
        int best = -1;
        for (int x = 0; x < 8; ++x)
          if (bincnt[x] + nb <= 320 && (best < 0 || binload[x] < binload[best])) best = x;
        if (best < 0) best = 0;
        sh_ax[na] = best; sh_apos[na] = bincnt[best];
        sh_ah[na] = hh; sh_ab[na] = bb; sh_nb[na] = nb; ++na;
        bincnt[best] += nb;
        binload[best] += csth[hh];
      }
    }
    // loss
    float dv = sumh - 512.0f;
    float floss = dv * dv;
    float rsum = 0.f;
    for (int i = 0; i < 6; ++i) rsum += fmaxf(8.0f - hdf[i], 0.0f);
    floss += rsum / 6.0f;
    float il = 0.f;
    for (int i = 0; i < 6; ++i) { float dd = hdf[i] - (float)hdi[i]; il += dd * dd; }
    il /= 6.0f;
    loss_out[0] = floss + 0.5f * il;
  }
  __syncthreads();

  for (int col = tid; col < 512; col += 64) {
    int hh = 5;
    for (int i = 0; i < 5; ++i) if (col < sh_starts[i + 1]) { hh = i; break; }
    int qc = sh_astarts[hh] + (col - sh_starts[hh]);
    cmap[col] = qc;
    cmap[512 + col] = QKSTRIDE + qc;
    cmap[1024 + col] = 4096 + col;
    cmap[1536 + col] = hh;
  }
  for (int e = tid; e < 2560; e += 64) sched[e] = -1;
  __syncthreads();
  for (int e = tid; e < 24 * 128; e += 64) {
    const int a = e >> 7, qi = e & 127;
    if (qi < sh_nb[a])
      sched[sh_ax[a] + 8 * (sh_apos[a] + qi)] = sh_ah[a] | (sh_ab[a] << 4) | (qi << 8);
  }
}

// ---------------- converters ----------------
__global__ void conv_bf16_kernel(const float* __restrict__ x, unsigned short* __restrict__ y, int n4) {
  int i = blockIdx.x * blockDim.x + threadIdx.x;
  if (i >= n4) return;
  float4 v = reinterpret_cast<const float4*>(x)[i];
  union { unsigned short u[4]; uint2 q; } o;
  o.u[0] = f2bf(v.x); o.u[1] = f2bf(v.y); o.u[2] = f2bf(v.z); o.u[3] = f2bf(v.w);
  reinterpret_cast<uint2*>(y)[i] = o.q;
}

// coalesced LDS-tiled transpose: WT[n][k] = bf16(W[k][n]); z=0: w_qkv (N=1536), z=1: w_out (N=512)
__global__ void convWT2_kernel(const float* __restrict__ Wqkv, const float* __restrict__ Wout,
                               unsigned short* __restrict__ wqkvT, unsigned short* __restrict__ woutT) {
  __shared__ float tile[64][65];
  const int mz = blockIdx.z;
  if (mz && blockIdx.y >= 8) return;
  const int N = mz ? 512 : 1536;
  const float* W = mz ? Wout : Wqkv;
  unsigned short* WT = mz ? woutT : wqkvT;
  const int k0 = blockIdx.x * 64, n0 = blockIdx.y * 64;
  const int t = threadIdx.x;
  {
    const int c = (t & 15) * 4;
#pragma unroll
    for (int rp = 0; rp < 4; ++rp) {
      const int r = rp * 16 + (t >> 4);
      float4 v = *reinterpret_cast<const float4*>(&W[(size_t)(k0 + r) * N + n0 + c]);
      tile[r][c] = v.x; tile[r][c + 1] = v.y; tile[r][c + 2] = v.z; tile[r][c + 3] = v.w;
    }
  }
  __syncthreads();
  {
    const int n = t >> 2, kc = (t & 3) * 16;
    unsigned short outv[16];
#pragma unroll
    for (int j = 0; j < 16; ++j) outv[j] = f2bf(tile[kc + j][n]);
    unsigned short* dst = &WT[(size_t)(n0 + n) * 512 + k0 + kc];
    *reinterpret_cast<u16x8*>(dst) = *reinterpret_cast<u16x8*>(&outv[0]);
    *reinterpret_cast<u16x8*>(dst + 8) = *reinterpret_cast<u16x8*>(&outv[8]);
  }
}

// ---------------- GEMM: C[M][N] = A[M][K](bf16) @ Bt[N][K]^T + bias ----------------
template<int MODE>
__global__ __launch_bounds__(256, 2) void gemm_bt(
    const unsigned short* __restrict__ A,
    const unsigned short* __restrict__ Bt,
    const float* __restrict__ bias,
    float* __restrict__ Cf,
    unsigned short* __restrict__ qkpad,
    unsigned short* __restrict__ VtOut,
    const int* __restrict__ cmap,
    int N, int K)
{
  __shared__ unsigned short As[128 * 32];
  __shared__ unsigned short Bs[128 * 32];
  const int tid = threadIdx.x;
  const int wave = tid >> 6, lane = tid & 63;
  const int lrow = lane & 15, lgrp = lane >> 4;
  const int wm = wave >> 1, wn = wave & 1;
  const int brow = blockIdx.y * 128;
  const int bcol = blockIdx.x * 128;

  f32x4 acc[4][4];
#pragma unroll
  for (int m = 0; m < 4; ++m)
#pragma unroll
    for (int n = 0; n < 4; ++n) acc[m][n] = (f32x4){0.f, 0.f, 0.f, 0.f};

  const int sig0 = wave * 128 + lane;
  for (int kb = 0; kb < K; kb += 32) {
    __syncthreads();
#pragma unroll
    for (int it = 0; it < 2; ++it) {
      const int sigma = sig0 + it * 64;
      const int r = sigma >> 2, sp = sigma & 3;
      const int sl = sp ^ ((r >> 1) & 3);
      gload_lds16(&A[(size_t)(brow + r) * K + kb + sl * 8], &As[sigma * 8]);
    }
#pragma unroll
    for (int it = 0; it < 2; ++it) {
      const int sigma = sig0 + it * 64;
      const int r = sigma >> 2, sp = sigma & 3;
      const int sl = sp ^ ((r >> 1) & 3);
      gload_lds16(&Bt[(size_t)(bcol + r) * K + kb + sl * 8], &Bs[sigma * 8]);
    }
    __syncthreads();
    const int sub = (lgrp ^ ((lrow >> 1) & 3)) * 8;
    bf16x8 aF[4], bF[4];
#pragma unroll
    for (int m = 0; m < 4; ++m)
      aF[m] = *reinterpret_cast<const bf16x8*>(&As[(wm * 64 + m * 16 + lrow) * 32 + sub]);
#pragma unroll
    for (int n = 0; n < 4; ++n)
      bF[n] = *reinterpret_cast<const bf16x8*>(&Bs[(wn * 64 + n * 16 + lrow) * 32 + sub]);
#pragma unroll
    for (int m = 0; m < 4; ++m)
#pragma unroll
      for (int n = 0; n < 4; ++n)
        acc[m][n] = __builtin_amdgcn_mfma_f32_16x16x32_bf16(aF[m], bF[n], acc[m][n], 0, 0, 0);
  }

#pragma unroll
  for (int n = 0; n < 4; ++n) {
    const int col = bcol + wn * 64 + n * 16 + lrow;
    const float bv = bias[col];
    int mc = 0;
    if (MODE == 1) mc = cmap[col];
#pragma unroll
    for (int m = 0; m < 4; ++m) {
      if (MODE == 0) {
#pragma unroll
        for (int r = 0; r < 4; ++r) {
          const int row = brow + wm * 64 + m * 16 + lgrp * 4 + r;
          Cf[(size_t)row * N + col] = acc[m][n][r] + bv;
        }
      } else if (mc < 4096) {
#pragma unroll
        for (int r = 0; r < 4; ++r) {
          const int row = brow + wm * 64 + m * 16 + lgrp * 4 + r;
          qkpad[(size_t)row * QKROW + mc] = f2bf(acc[m][n][r] + bv);
        }
      } else {
        // V: transpose on the fly. Rows are 4 consecutive t -> one 8B packed store.
        const int t0g = brow + wm * 64 + m * 16 + lgrp * 4;
        const int b = t0g >> 11, t0 = t0g & 2047;
        uint2 w;
        w.x = pack2bf(acc[m][n][0] + bv, acc[m][n][1] + bv);
        w.y = pack2bf(acc[m][n][2] + bv, acc[m][n][3] + bv);
        *reinterpret_cast<uint2*>(&VtOut[(size_t)(b * VTPAD + (mc - 4096)) * 2048 + t0]) = w;
      }
    }
  }
}

// ---------------- split-K flash attention; NS=2: wave pairs split d-tiles (big heads) ----------------
template<int NC, int NS>
static __device__ __forceinline__ void attn_body(
    const unsigned short* __restrict__ qkpad,
    const unsigned short* __restrict__ Vt,
    unsigned short* __restrict__ Op,
    float2* __restrict__ mlArr,
    int b, int q0, int d, int start, int astart, int kh, int mlBase, int dh,
    unsigned char* KsB, unsigned int* PlW,
    int wave, int lane)
{
  constexpr int S = (4 * NC + 7) & ~7;
  constexpr int NTW = (NS == 2) ? 8 : 2 * NC;   // d-tiles this wave owns (NS=1: NC<=4 -> <=8)
  constexpr int BATCH = (NS == 2) ? 4 : 8;
  constexpr int KI = S / 8;
  constexpr int KTILE = 32 * S * 16;
  const int TT0 = dh * 8;                        // global tile offset for this wave
  int ntw = ((d + 15) >> 4) - TT0;
  if (ntw > NTW) ntw = NTW;
  const int lrow = lane & 15, lgrp = lane >> 4;
  const float scale = 1.0f / sqrtf((float)d);

  bf16x8 qf[NC];
  {
    const unsigned short* qp = qkpad + (size_t)(b * 2048 + q0 + lrow) * QKROW + astart + lgrp * 8;
#pragma unroll
    for (int dc = 0; dc < NC; ++dc) {
      bf16x8 v = *reinterpret_cast<const bf16x8*>(qp + dc * 32);
#pragma unroll
      for (int j = 0; j < 8; ++j)
        if (dc * 32 + lgrp * 8 + j >= d) v[j] = (__bf16)0.0f;
      qf[dc] = v;
    }
  }

  const unsigned short* kPtr[KI];
  int kDstB[KI];
#pragma unroll
  for (int j = 0; j < KI; ++j) {
    const int g = (wave * KI + j) * 64 + lane;
    const int r = g / S, pp = g - r * S;
    const int sp = pp ^ (r & 7);
    kPtr[j] = qkpad + (size_t)(b * 2048 + kh * 1024 + r) * QKROW + QKSTRIDE + astart + sp * 8;
    kDstB[j] = g * 16;
  }

  const unsigned short* vRow = Vt + (size_t)(b * VTPAD + start + TT0 * 16 + lrow) * 2048 + kh * 1024 + lgrp * 8;

  f32x4 acc[NTW];
#pragma unroll
  for (int t = 0; t < NTW; ++t) acc[t] = (f32x4){0.f, 0.f, 0.f, 0.f};
  float m_run = -1e30f, l_run = 0.f;

#pragma unroll
  for (int j = 0; j < KI; ++j) gload_lds16(kPtr[j], KsB + kDstB[j]);
#pragma unroll
  for (int j = 0; j < KI; ++j) kPtr[j] += 32 * QKROW;
  __syncthreads();

  for (int i = 0; i < 32; ++i) {
    const int kt = i << 5;
    const int cur = i & 1;
    if (i < 31) {
      unsigned char* kd = KsB + (cur ^ 1) * KTILE;
#pragma unroll
      for (int j = 0; j < KI; ++j) gload_lds16(kPtr[j], kd + kDstB[j]);
#pragma unroll
      for (int j = 0; j < KI; ++j) kPtr[j] += 32 * QKROW;
    }

    f32x4 s4[2];
    s4[0] = (f32x4){0.f, 0.f, 0.f, 0.f};
    s4[1] = (f32x4){0.f, 0.f, 0.f, 0.f};
    const unsigned char* kB = KsB + cur * KTILE;
    const int swz = lrow & 7;
    __builtin_amdgcn_s_setprio(1);
#pragma unroll
    for (int dc = 0; dc < NC; ++dc) {
#pragma unroll
      for (int t = 0; t < 2; ++t) {
        const bf16x8 kf = *reinterpret_cast<const bf16x8*>(
            kB + (t * 16 + lrow) * (S * 16) + (((dc * 4 + lgrp) ^ swz) * 16));
        s4[t] = __builtin_amdgcn_mfma_f32_16x16x32_bf16(kf, qf[dc], s4[t], 0, 0, 0);
      }
    }
    __builtin_amdgcn_s_setprio(0);

    float ps[8];
#pragma unroll
    for (int t = 0; t < 2; ++t)
#pragma unroll
      for (int r = 0; r < 4; ++r) ps[t * 4 + r] = s4[t][r] * scale;
    float pm = ps[0];
#pragma unroll
    for (int z = 1; z < 8; ++z) pm = fmaxf(pm, ps[z]);
    pm = fmaxf(pm, __shfl_xor(pm, 16));
    pm = fmaxf(pm, __shfl_xor(pm, 32));
    if (__any(pm > m_run + 8.0f)) {
      const float mn = fmaxf(m_run, pm);
      const float alpha = __expf(m_run - mn);
      m_run = mn; l_run *= alpha;
      float al4[4];
#pragma unroll
      for (int r = 0; r < 4; ++r) al4[r] = __shfl(alpha, lgrp * 4 + r);
#pragma unroll
      for (int t = 0; t < NTW; ++t) {
        if (t < ntw) {
#pragma unroll
          for (int r = 0; r < 4; ++r) acc[t][r] *= al4[r];
        }
      }
    }
    float sum = 0.f;
#pragma unroll
    for (int z = 0; z < 8; ++z) { ps[z] = __expf(ps[z] - m_run); sum += ps[z]; }
    sum += __shfl_xor(sum, 16);
    sum += __shfl_xor(sum, 32);
    l_run += sum;

#pragma unroll
    for (int t = 0; t < 2; ++t) {
      uint2 w;
      w.x = pack2bf(ps[t * 4 + 0], ps[t * 4 + 1]);
      w.y = pack2bf(ps[t * 4 + 2], ps[t * 4 + 3]);
      *reinterpret_cast<uint2*>(PlW + lrow * 20 + 8 * t + 2 * lgrp) = w;
    }
    asm volatile("s_waitcnt lgkmcnt(0)" ::: "memory");
    __builtin_amdgcn_sched_barrier(0);
    const bf16x8 pa = *reinterpret_cast<const bf16x8*>(PlW + lrow * 20 + 4 * lgrp);

#pragma unroll
    for (int t0 = 0; t0 < NTW; t0 += BATCH) {
      bf16x8 vf[BATCH];
#pragma unroll
      for (int j = 0; j < BATCH; ++j) {
        const int t = t0 + j;
        if (t < NTW && t < ntw)
          vf[j] = *reinterpret_cast<const bf16x8*>(vRow + (size_t)t * 32768 + kt);
      }
      __builtin_amdgcn_s_setprio(1);
#pragma unroll
      for (int j = 0; j < BATCH; ++j) {
        const int t = t0 + j;
        if (t < NTW && t < ntw)
          acc[t] = __builtin_amdgcn_mfma_f32_16x16x32_bf16(pa, vf[j], acc[t], 0, 0, 0);
      }
      __builtin_amdgcn_s_setprio(0);
    }
    __syncthreads();
  }

  float invl[4];
#pragma unroll
  for (int r = 0; r < 4; ++r) invl[r] = 1.0f / __shfl(l_run, lgrp * 4 + r);
#pragma unroll
  for (int t = 0; t < NTW; ++t) {
    if (t < ntw) {
      const int col = (TT0 + t) * 16 + lrow;
      if (col < d) {
#pragma unroll
        for (int r = 0; r < 4; ++r) {
          Op[(size_t)(b * 2048 + q0 + lgrp * 4 + r) * 512 + start + col] =
              f2bf(acc[t][r] * invl[r]);
        }
      }
    }
  }
  if (lgrp == 0 && (NS == 1 || dh == 0)) mlArr[mlBase + lrow] = make_float2(m_run, l_run);
}

__global__ __launch_bounds__(256, 4) void attn_fused(
    const unsigned short* __restrict__ qkpad,
    const unsigned short* __restrict__ Vt,
    unsigned short* __restrict__ O0,
    unsigned short* __restrict__ O1,
    float2* __restrict__ mlArr,
    const int* __restrict__ hdr,
    const int* __restrict__ sched)
{
  __shared__ __align__(16) unsigned char KsB[32768];
  __shared__ unsigned int Pl[4][16 * 20];

  const int sv = sched[blockIdx.x];
  if (sv < 0) return;
  const int h = sv & 15, b = (sv >> 4) & 15;
  const int qi = (sv >> 8) & 255;
  const int d = hdr[h];
  const int nc = (d + 31) >> 5;
  if (nc > 8) return;
  const int start = hdr[8 + h];
  const int astart = hdr[16 + h];
  const int wave = threadIdx.x >> 6, lane = threadIdx.x & 63;
  unsigned int* PlW = &Pl[wave][0];

  if (nc <= 4) {
    const int kh = qi >> 5;                       // qi in 0..63
    const int q0 = (qi & 31) * 64 + wave * 16;
    unsigned short* Op = kh ? O1 : O0;
    const int mlBase = (kh * 24 + h * 4 + b) * 2048 + q0;
    switch (nc) {
      case 1: attn_body<1, 1>(qkpad, Vt, Op, mlArr, b, q0, d, start, astart, kh, mlBase, 0, KsB, PlW, wave, lane); break;
      case 2: attn_body<2, 1>(qkpad, Vt, Op, mlArr, b, q0, d, start, astart, kh, mlBase, 0, KsB, PlW, wave, lane); break;
      case 3: attn_body<3, 1>(qkpad, Vt, Op, mlArr, b, q0, d, start, astart, kh, mlBase, 0, KsB, PlW, wave, lane); break;
      case 4: attn_body<4, 1>(qkpad, Vt, Op, mlArr, b, q0, d, start, astart, kh, mlBase, 0, KsB, PlW, wave, lane); break;
      default: break;
    }
  } else {
    const int kh = qi >> 6;                       // qi in 0..127
    const int q0 = (qi & 63) * 32 + (wave >> 1) * 16;
    const int dh = wave & 1;
    unsigned short* Op = kh ? O1 : O0;
    const int mlBase = (kh * 24 + h * 4 + b) * 2048 + q0;
    switch (nc) {
      case 5: attn_body<5, 2>(qkpad, Vt, Op, mlArr, b, q0, d, start, astart, kh, mlBase, dh, KsB, PlW, wave, lane); break;
      case 6: attn_body<6, 2>(qkpad, Vt, Op, mlArr, b, q0, d, start, astart, kh, mlBase, dh, KsB, PlW, wave, lane); break;
      case 7: attn_body<7, 2>(qkpad, Vt, Op, mlArr, b, q0, d, start, astart, kh, mlBase, dh, KsB, PlW, wave, lane); break;
      case 8: attn_body<8, 2>(qkpad, Vt, Op, mlArr, b, q0, d, start, astart, kh, mlBase, dh, KsB, PlW, wave, lane); break;
      default: break;
    }
  }
}

// ---------------- merge v2: per-(b,h) blocks; ratio computed once per row ----------------
__global__ __launch_bounds__(256) void merge_kernel(
    const unsigned short* __restrict__ O0,
    const unsigned short* __restrict__ O1,
    const float2* __restrict__ mlArr,
    unsigned short* __restrict__ attnC,
    const int* __restrict__ hdr)
{
  const int sh = blockIdx.y;                 // 0..23
  const int h = sh >> 2, b = sh & 3;
  const int d = hdr[h];
  if (((d + 31) >> 5) > 8) return;           // fallback path owns these
  const int start = hdr[8 + h];
  const int q = blockIdx.x * 32 + (threadIdx.x >> 3);
  const int cg = threadIdx.x & 7;
  const float2 A = mlArr[(h * 4 + b) * 2048 + q];
  const float2 B = mlArr[(24 + h * 4 + b) * 2048 + q];
  const float M = fmaxf(A.x, B.x);
  const float a1 = __expf(A.x - M) * A.y;
  const float a2 = __expf(B.x - M) * B.y;
  const float inv = 1.0f / (a1 + a2);
  const float r1 = a1 * inv, r2 = a2 * inv;
  const size_t base = (size_t)(b * 2048 + q) * 512 + start;
  for (int c = cg; c < d; c += 8)
    attnC[base + c] = f2bf(r1 * bf2f(O0[base + c]) + r2 * bf2f(O1[base + c]));
}

// ---------------- direct fallback for nc>8 (d>256), normally all-exit ----------------
template<int NCLO, int NCHI>
__global__ __launch_bounds__(256, 2) void attn_kernel(
    const unsigned short* __restrict__ qkpad,
    const unsigned short* __restrict__ Vt,
    unsigned short* __restrict__ attnC,
    const int* __restrict__ hdr)
{
  const int h = blockIdx.y, b = blockIdx.z;
  const int d = hdr[h];
  const int nc = (d + 31) >> 5;
  if (nc <= NCLO || nc > NCHI) return;
  const int start = hdr[8 + h];
  const int astart = hdr[16 + h];
  const int wave = threadIdx.x >> 6;
  const int lane = threadIdx.x & 63;
  const int lrow = lane & 15, lgrp = lane >> 4;
  const int q0 = blockIdx.x * 64 + wave * 16;
  const int ntiles = (d + 15) >> 4;
  const float scale = 1.0f / sqrtf((float)d);

  __shared__ unsigned short Pl[2][4][16 * 32];

  bf16x8 qf[NCHI];
  {
    const size_t qbase = (size_t)(b * 2048 + q0 + lrow) * QKROW + astart;
#pragma unroll
    for (int dc = 0; dc < NCHI; ++dc) {
      if (dc < nc) {
        bf16x8 v = *reinterpret_cast<const bf16x8*>(&qkpad[qbase + dc * 32 + lgrp * 8]);
#pragma unroll
        for (int j = 0; j < 8; ++j)
          if (dc * 32 + lgrp * 8 + j >= d) v[j] = (__bf16)0.0f;
        qf[dc] = v;
      }
    }
  }

  f32x4 acc[2 * NCHI];
#pragma unroll
  for (int t = 0; t < 2 * NCHI; ++t) acc[t] = (f32x4){0.f, 0.f, 0.f, 0.f};
  float m_run[4] = {-1e30f, -1e30f, -1e30f, -1e30f};
  float l_run[4] = {0.f, 0.f, 0.f, 0.f};

  for (int kt = 0; kt < 2048; kt += 32) {
    f32x4 s0 = {0.f, 0.f, 0.f, 0.f}, s1 = {0.f, 0.f, 0.f, 0.f};
    const size_t kb0 = (size_t)(b * 2048 + kt + lrow) * QKROW + QKSTRIDE + astart;
    const size_t kb1 = kb0 + (size_t)16 * QKROW;
#pragma unroll
    for (int dc = 0; dc < NCHI; ++dc) {
      if (dc < nc) {
        bf16x8 k0 = *reinterpret_cast<const bf16x8*>(&qkpad[kb0 + dc * 32 + lgrp * 8]);
        bf16x8 k1 = *reinterpret_cast<const bf16x8*>(&qkpad[kb1 + dc * 32 + lgrp * 8]);
        s0 = __builtin_amdgcn_mfma_f32_16x16x32_bf16(qf[dc], k0, s0, 0, 0, 0);
        s1 = __builtin_amdgcn_mfma_f32_16x16x32_bf16(qf[dc], k1, s1, 0, 0, 0);
      }
    }
    float p0[4], p1[4], pmax[4];
#pragma unroll
    for (int r = 0; r < 4; ++r) {
      p0[r] = s0[r] * scale; p1[r] = s1[r] * scale;
      float mx = fmaxf(p0[r], p1[r]);
#pragma unroll
      for (int off = 1; off < 16; off <<= 1) mx = fmaxf(mx, __shfl_xor(mx, off));
      pmax[r] = mx;
    }
    bool need = false;
#pragma unroll
    for (int r = 0; r < 4; ++r) need = need || (pmax[r] > m_run[r] + 8.0f);
    if (__any(need)) {
#pragma unroll
      for (int r = 0; r < 4; ++r) {
        float mn = fmaxf(m_run[r], pmax[r]);
        float al = __expf(m_run[r] - mn);
        m_run[r] = mn; l_run[r] *= al;
#pragma unroll
        for (int t = 0; t < 2 * NCHI; ++t)
          if (t < ntiles) acc[t][r] *= al;
      }
    }
#pragma unroll
    for (int r = 0; r < 4; ++r) {
      p0[r] = __expf(p0[r] - m_run[r]);
      p1[r] = __expf(p1[r] - m_run[r]);
      float sm = p0[r] + p1[r];
#pragma unroll
      for (int off = 1; off < 16; off <<= 1) sm += __shfl_xor(sm, off);
      l_run[r] += sm;
    }
    const int pb = (kt >> 5) & 1;
    unsigned short* P = &Pl[pb][wave][0];
#pragma unroll
    for (int r = 0; r < 4; ++r) {
      P[(lgrp * 4 + r) * 32 + lrow] = f2bf(p0[r]);
      P[(lgrp * 4 + r) * 32 + 16 + lrow] = f2bf(p1[r]);
    }
    asm volatile("s_waitcnt lgkmcnt(0)" ::: "memory");
    bf16x8 pf = *reinterpret_cast<const bf16x8*>(&P[lrow * 32 + lgrp * 8]);
    const size_t vbase = (size_t)(b * VTPAD + start) * 2048 + kt + lgrp * 8;
#pragma unroll
    for (int t = 0; t < 2 * NCHI; ++t) {
      if (t < ntiles) {
        bf16x8 vf = *reinterpret_cast<const bf16x8*>(&Vt[vbase + (size_t)(t * 16 + lrow) * 2048]);
        acc[t] = __builtin_amdgcn_mfma_f32_16x16x32_bf16(pf, vf, acc[t], 0, 0, 0);
      }
    }
  }

  float inv[4];
#pragma unroll
  for (int r = 0; r < 4; ++r) inv[r] = 1.0f / l_run[r];
#pragma unroll
  for (int t = 0; t < 2 * NCHI; ++t) {
    if (t < ntiles) {
      int col = t * 16 + lrow;
      if (col < d) {
#pragma unroll
        for (int r = 0; r < 4; ++r) {
          attnC[(size_t)(b * 2048 + q0 + lgrp * 4 + r) * 512 + start + col] =
              f2bf(acc[t][r] * inv[r]);
        }
      }
    }
  }
}

// ---------------- launch ----------------
extern "C" void kernel_launch(void* const* d_in, const int* in_sizes, int n_in,
                              void* d_out, int out_size, void* d_ws, size_t ws_size,
                              hipStream_t stream) {
  const float* query  = (const float*)d_in[0];
  const float* logits = (const float*)d_in[1];
  const float* w_qkv  = (const float*)d_in[2];
  const float* b_qkv  = (const float*)d_in[3];
  const float* w_out  = (const float*)d_in[4];
  const float* b_out  = (const float*)d_in[5];
  float* out = (float*)d_out;

  char* p = (char*)d_ws;
  size_t off = 0;
  auto alloc = [&](size_t bytes) {
    void* r = p + off; off += (bytes + 255) & ~(size_t)255; return r;
  };
  int* hdr              = (int*)alloc(1024);
  int* cmap             = (int*)alloc(2048 * 4);
  int* sched            = (int*)alloc(2560 * 4);
  unsigned short* qbf   = (unsigned short*)alloc((size_t)8192 * 512 * 2);   // reused as O0
  unsigned short* wqkvT = (unsigned short*)alloc((size_t)1536 * 512 * 2);
  unsigned short* woutT = (unsigned short*)alloc((size_t)512 * 512 * 2);
  unsigned short* qkpad = (unsigned short*)alloc((size_t)8192 * QKROW * 2 + 4096);
  unsigned short* vbuf  = (unsigned short*)alloc((size_t)8192 * 512 * 2);   // reused as O1
  unsigned short* Vt    = (unsigned short*)alloc((size_t)4 * VTPAD * 2048 * 2 + 4096);
  unsigned short* attnC = (unsigned short*)alloc((size_t)8192 * 512 * 2);
  float2* mlArr         = (float2*)alloc((size_t)2 * 24 * 2048 * 8);
  (void)ws_size; (void)in_sizes; (void)n_in; (void)out_size;

  prep_kernel<<<1, 64, 0, stream>>>(logits, hdr, cmap, sched, out + 4194304);
  conv_bf16_kernel<<<4096, 256, 0, stream>>>(query, qbf, 8192 * 512 / 4);
  convWT2_kernel<<<dim3(8, 24, 2), 256, 0, stream>>>(w_qkv, w_out, wqkvT, woutT);
  gemm_bt<1><<<dim3(12, 64), 256, 0, stream>>>(qbf, wqkvT, b_qkv, nullptr, qkpad, Vt, cmap, 1536, 512);
  // qbf/vbuf dead from here -> reuse as split-K partial buffers O0/O1 (transV fused into gemm)
  attn_fused<<<dim3(2560, 1, 1), 256, 0, stream>>>(qkpad, Vt, qbf, vbuf, mlArr, hdr, sched);
  attn_kernel<8, 15><<<dim3(32, 6, 4), 256, 0, stream>>>(qkpad, Vt, attnC, hdr);
  merge_kernel<<<dim3(64, 24), 256, 0, stream>>>(qbf, vbuf, mlArr, attnC, hdr);
  gemm_bt<0><<<dim3(4, 64), 256, 0, stream>>>(attnC, woutT, b_out, out, nullptr, nullptr, nullptr, 512, 512);
}

// Round 16
// 285.265 us; speedup vs baseline: 1.0432x; 1.0432x over previous
//
#include <hip/hip_runtime.h>
#include <hip/hip_bf16.h>
#include <cstdint>

typedef __attribute__((ext_vector_type(8))) __bf16 bf16x8;
typedef __attribute__((ext_vector_type(8))) unsigned short u16x8;
typedef __attribute__((ext_vector_type(4))) float f32x4;

#define QKSTRIDE 640
#define QKROW 1280
#define VTPAD 528

static __device__ __forceinline__ unsigned short f2bf(float f) {
  __hip_bfloat16 h = __float2bfloat16(f);
  return *reinterpret_cast<unsigned short*>(&h);
}
static __device__ __forceinline__ float bf2f(unsigned short u) {
  union { unsigned v; float f; } c; c.v = ((unsigned)u) << 16; return c.f;
}
static __device__ __forceinline__ unsigned pack2bf(float a, float b) {
  return (unsigned)f2bf(a) | ((unsigned)f2bf(b) << 16);
}

static __device__ __forceinline__ void gload_lds16(const void* g, void* lds) {
  __builtin_amdgcn_global_load_lds(
      (const __attribute__((address_space(1))) unsigned int*)g,
      (__attribute__((address_space(3))) unsigned int*)lds, 16, 0, 0);
}

// ---------------- prep: head dims, loss, column maps, split-K schedule (parallel; R9) ----------------
__global__ void prep_kernel(const float* __restrict__ logits, int* __restrict__ hdr,
                            int* __restrict__ cmap, int* __restrict__ sched,
                            float* __restrict__ loss_out) {
  __shared__ int sh_starts[8], sh_astarts[8];
  __shared__ int sh_ax[24], sh_apos[24], sh_ah[24], sh_ab[24];
  const int tid = threadIdx.x;
  if (blockIdx.x != 0) return;

  if (tid == 0) {
    float l[6]; float mx = -1e30f;
    for (int i = 0; i < 6; ++i) { l[i] = logits[i]; mx = fmaxf(mx, l[i]); }
    float e[6]; float s = 0.f;
    for (int i = 0; i < 6; ++i) { e[i] = expf(l[i] - mx); s += e[i]; }
    float hdf[6]; float sumh = 0.f;
    for (int i = 0; i < 6; ++i) { hdf[i] = 8.0f + (e[i] / s) * 464.0f; sumh += hdf[i]; }
    int hdi[6]; float res[6]; int isum = 0;
    for (int i = 0; i < 6; ++i) {
      float fl = floorf(hdf[i]);
      hdi[i] = (int)fl; res[i] = hdf[i] - fl; isum += hdi[i];
    }
    int diff = 512 - isum;
    bool used[6] = {false, false, false, false, false, false};
    if (diff > 0) {
      for (int t = 0; t < diff; ++t) {
        int best = -1; float bv = -1e30f;
        for (int i = 0; i < 6; ++i) if (!used[i] && res[i] > bv) { bv = res[i]; best = i; }
        used[best] = true; hdi[best] += 1;
      }
    } else if (diff < 0) {
      for (int t = 0; t < -diff; ++t) {
        int best = -1; float bv = 1e30f;
        for (int i = 0; i < 6; ++i) if (!used[i] && res[i] < bv) { bv = res[i]; best = i; }
        used[best] = true; hdi[best] -= 1;
      }
    }
    { int st = 0, ast = 0;
      for (int i = 0; i < 6; ++i) {
        sh_starts[i] = st; sh_astarts[i] = ast;
        hdr[i] = hdi[i]; hdr[8 + i] = st; hdr[16 + i] = ast;
        st += hdi[i]; ast += (hdi[i] + 7) & ~7;
      }
      sh_starts[6] = st; sh_starts[7] = st;
    }
    // LPT: 24 (h,b) sets, 64 blocks each, 8 XCD bins cap 192
    int csth[6];
    for (int i = 0; i < 6; ++i) {
      int ncl = (hdi[i] + 31) / 32;
      int ntl = (hdi[i] + 15) / 16;
      csth[i] = 4 * ncl + 2 * ntl + 8;
    }
    int ord[6] = {0, 1, 2, 3, 4, 5};
    for (int a = 0; a < 6; ++a)
      for (int c = a + 1; c < 6; ++c)
        if (csth[ord[c]] > csth[ord[a]]) { int t = ord[a]; ord[a] = ord[c]; ord[c] = t; }
    int binload[8], bincnt[8];
    for (int x = 0; x < 8; ++x) { binload[x] = 0; bincnt[x] = 0; }
    int na = 0;
    for (int a = 0; a < 6; ++a) {
      const int hh = ord[a];
      for (int bb = 0; bb < 4; ++bb) {
        int best = -1;
        for (int x = 0; x < 8; ++x)
          if (bincnt[x] + 64 <= 192 && (best < 0 || binload[x] < binload[best])) best = x;
        if (best < 0) best = 0;
        sh_ax[na] = best; sh_apos[na] = bincnt[best];
        sh_ah[na] = hh; sh_ab[na] = bb; ++na;
        bincnt[best] += 64;
        binload[best] += csth[hh];
      }
    }
    // loss
    float dv = sumh - 512.0f;
    float floss = dv * dv;
    float rsum = 0.f;
    for (int i = 0; i < 6; ++i) rsum += fmaxf(8.0f - hdf[i], 0.0f);
    floss += rsum / 6.0f;
    float il = 0.f;
    for (int i = 0; i < 6; ++i) { float dd = hdf[i] - (float)hdi[i]; il += dd * dd; }
    il /= 6.0f;
    loss_out[0] = floss + 0.5f * il;
  }
  __syncthreads();

  for (int col = tid; col < 512; col += 64) {
    int hh = 5;
    for (int i = 0; i < 5; ++i) if (col < sh_starts[i + 1]) { hh = i; break; }
    int qc = sh_astarts[hh] + (col - sh_starts[hh]);
    cmap[col] = qc;
    cmap[512 + col] = QKSTRIDE + qc;
    cmap[1024 + col] = 4096 + col;
    cmap[1536 + col] = hh;
  }
  for (int e = tid; e < 1536; e += 64) sched[e] = -1;
  __syncthreads();
  for (int e = tid; e < 24 * 64; e += 64) {
    const int a = e >> 6, qi = e & 63;
    sched[sh_ax[a] + 8 * (sh_apos[a] + qi)] = sh_ah[a] | (sh_ab[a] << 4) | (qi << 8);
  }
}

// ---------------- converters ----------------
__global__ void conv_bf16_kernel(const float* __restrict__ x, unsigned short* __restrict__ y, int n4) {
  int i = blockIdx.x * blockDim.x + threadIdx.x;
  if (i >= n4) return;
  float4 v = reinterpret_cast<const float4*>(x)[i];
  union { unsigned short u[4]; uint2 q; } o;
  o.u[0] = f2bf(v.x); o.u[1] = f2bf(v.y); o.u[2] = f2bf(v.z); o.u[3] = f2bf(v.w);
  reinterpret_cast<uint2*>(y)[i] = o.q;
}

// coalesced LDS-tiled transpose: WT[n][k] = bf16(W[k][n]); z=0: w_qkv (N=1536), z=1: w_out (N=512)
__global__ void convWT2_kernel(const float* __restrict__ Wqkv, const float* __restrict__ Wout,
                               unsigned short* __restrict__ wqkvT, unsigned short* __restrict__ woutT) {
  __shared__ float tile[64][65];
  const int mz = blockIdx.z;
  if (mz && blockIdx.y >= 8) return;
  const int N = mz ? 512 : 1536;
  const float* W = mz ? Wout : Wqkv;
  unsigned short* WT = mz ? woutT : wqkvT;
  const int k0 = blockIdx.x * 64, n0 = blockIdx.y * 64;
  const int t = threadIdx.x;
  {
    const int c = (t & 15) * 4;
#pragma unroll
    for (int rp = 0; rp < 4; ++rp) {
      const int r = rp * 16 + (t >> 4);
      float4 v = *reinterpret_cast<const float4*>(&W[(size_t)(k0 + r) * N + n0 + c]);
      tile[r][c] = v.x; tile[r][c + 1] = v.y; tile[r][c + 2] = v.z; tile[r][c + 3] = v.w;
    }
  }
  __syncthreads();
  {
    const int n = t >> 2, kc = (t & 3) * 16;
    unsigned short outv[16];
#pragma unroll
    for (int j = 0; j < 16; ++j) outv[j] = f2bf(tile[kc + j][n]);
    unsigned short* dst = &WT[(size_t)(n0 + n) * 512 + k0 + kc];
    *reinterpret_cast<u16x8*>(dst) = *reinterpret_cast<u16x8*>(&outv[0]);
    *reinterpret_cast<u16x8*>(dst + 8) = *reinterpret_cast<u16x8*>(&outv[8]);
  }
}

// ---------------- GEMM: C[M][N] = A[M][K](bf16) @ Bt[N][K]^T + bias ----------------
// MODE 0: f32 out. MODE 1: bf16 scatter; Q/K via cmap to qkpad, V written TRANSPOSED
// into Vt (packed 4x bf16 per store: per-thread rows are 4 consecutive t).
template<int MODE>
__global__ __launch_bounds__(256, 2) void gemm_bt(
    const unsigned short* __restrict__ A,
    const unsigned short* __restrict__ Bt,
    const float* __restrict__ bias,
    float* __restrict__ Cf,
    unsigned short* __restrict__ qkpad,
    unsigned short* __restrict__ VtOut,
    const int* __restrict__ cmap,
    int N, int K)
{
  __shared__ unsigned short As[128 * 32];
  __shared__ unsigned short Bs[128 * 32];
  const int tid = threadIdx.x;
  const int wave = tid >> 6, lane = tid & 63;
  const int lrow = lane & 15, lgrp = lane >> 4;
  const int wm = wave >> 1, wn = wave & 1;
  const int brow = blockIdx.y * 128;
  const int bcol = blockIdx.x * 128;

  f32x4 acc[4][4];
#pragma unroll
  for (int m = 0; m < 4; ++m)
#pragma unroll
    for (int n = 0; n < 4; ++n) acc[m][n] = (f32x4){0.f, 0.f, 0.f, 0.f};

  const int sig0 = wave * 128 + lane;
  for (int kb = 0; kb < K; kb += 32) {
    __syncthreads();
#pragma unroll
    for (int it = 0; it < 2; ++it) {
      const int sigma = sig0 + it * 64;
      const int r = sigma >> 2, sp = sigma & 3;
      const int sl = sp ^ ((r >> 1) & 3);
      gload_lds16(&A[(size_t)(brow + r) * K + kb + sl * 8], &As[sigma * 8]);
    }
#pragma unroll
    for (int it = 0; it < 2; ++it) {
      const int sigma = sig0 + it * 64;
      const int r = sigma >> 2, sp = sigma & 3;
      const int sl = sp ^ ((r >> 1) & 3);
      gload_lds16(&Bt[(size_t)(bcol + r) * K + kb + sl * 8], &Bs[sigma * 8]);
    }
    __syncthreads();
    const int sub = (lgrp ^ ((lrow >> 1) & 3)) * 8;
    bf16x8 aF[4], bF[4];
#pragma unroll
    for (int m = 0; m < 4; ++m)
      aF[m] = *reinterpret_cast<const bf16x8*>(&As[(wm * 64 + m * 16 + lrow) * 32 + sub]);
#pragma unroll
    for (int n = 0; n < 4; ++n)
      bF[n] = *reinterpret_cast<const bf16x8*>(&Bs[(wn * 64 + n * 16 + lrow) * 32 + sub]);
#pragma unroll
    for (int m = 0; m < 4; ++m)
#pragma unroll
      for (int n = 0; n < 4; ++n)
        acc[m][n] = __builtin_amdgcn_mfma_f32_16x16x32_bf16(aF[m], bF[n], acc[m][n], 0, 0, 0);
  }

#pragma unroll
  for (int n = 0; n < 4; ++n) {
    const int col = bcol + wn * 64 + n * 16 + lrow;
    const float bv = bias[col];
    int mc = 0;
    if (MODE == 1) mc = cmap[col];
#pragma unroll
    for (int m = 0; m < 4; ++m) {
      if (MODE == 0) {
#pragma unroll
        for (int r = 0; r < 4; ++r) {
          const int row = brow + wm * 64 + m * 16 + lgrp * 4 + r;
          Cf[(size_t)row * N + col] = acc[m][n][r] + bv;
        }
      } else if (mc < 4096) {
#pragma unroll
        for (int r = 0; r < 4; ++r) {
          const int row = brow + wm * 64 + m * 16 + lgrp * 4 + r;
          qkpad[(size_t)row * QKROW + mc] = f2bf(acc[m][n][r] + bv);
        }
      } else {
        // V: transpose on the fly. Rows are 4 consecutive t -> one 8B packed store.
        const int t0g = brow + wm * 64 + m * 16 + lgrp * 4;
        const int b = t0g >> 11, t0 = t0g & 2047;
        uint2 w;
        w.x = pack2bf(acc[m][n][0] + bv, acc[m][n][1] + bv);
        w.y = pack2bf(acc[m][n][2] + bv, acc[m][n][3] + bv);
        *reinterpret_cast<uint2*>(&VtOut[(size_t)(b * VTPAD + (mc - 4096)) * 2048 + t0]) = w;
      }
    }
  }
}

// ---------------- split-K flash attention (R9 body, unchanged) ----------------
template<int NC>
static __device__ __forceinline__ void attn_body(
    const unsigned short* __restrict__ qkpad,
    const unsigned short* __restrict__ Vt,
    unsigned short* __restrict__ Op,
    float2* __restrict__ mlArr,
    int b, int q0, int d, int start, int astart, int kh, int mlBase,
    unsigned char* KsB, unsigned int* PlW,
    int wave, int lane)
{
  constexpr int S = (4 * NC + 7) & ~7;
  constexpr int NT2 = 2 * NC;
  constexpr int KI = S / 8;
  constexpr int KTILE = 32 * S * 16;
  const int ntiles = (d + 15) >> 4;
  const int lrow = lane & 15, lgrp = lane >> 4;
  const float scale = 1.0f / sqrtf((float)d);

  bf16x8 qf[NC];
  {
    const unsigned short* qp = qkpad + (size_t)(b * 2048 + q0 + lrow) * QKROW + astart + lgrp * 8;
#pragma unroll
    for (int dc = 0; dc < NC; ++dc) {
      bf16x8 v = *reinterpret_cast<const bf16x8*>(qp + dc * 32);
#pragma unroll
      for (int j = 0; j < 8; ++j)
        if (dc * 32 + lgrp * 8 + j >= d) v[j] = (__bf16)0.0f;
      qf[dc] = v;
    }
  }

  const unsigned short* kPtr[KI];
  int kDstB[KI];
#pragma unroll
  for (int j = 0; j < KI; ++j) {
    const int g = (wave * KI + j) * 64 + lane;
    const int r = g / S, pp = g - r * S;
    const int sp = pp ^ (r & 7);
    kPtr[j] = qkpad + (size_t)(b * 2048 + kh * 1024 + r) * QKROW + QKSTRIDE + astart + sp * 8;
    kDstB[j] = g * 16;
  }

  const unsigned short* vRow = Vt + (size_t)(b * VTPAD + start + lrow) * 2048 + kh * 1024 + lgrp * 8;

  f32x4 acc[NT2];
#pragma unroll
  for (int t = 0; t < NT2; ++t) acc[t] = (f32x4){0.f, 0.f, 0.f, 0.f};
  float m_run = -1e30f, l_run = 0.f;

#pragma unroll
  for (int j = 0; j < KI; ++j) gload_lds16(kPtr[j], KsB + kDstB[j]);
#pragma unroll
  for (int j = 0; j < KI; ++j) kPtr[j] += 32 * QKROW;
  __syncthreads();

  for (int i = 0; i < 32; ++i) {
    const int kt = i << 5;
    const int cur = i & 1;
    if (i < 31) {
      unsigned char* kd = KsB + (cur ^ 1) * KTILE;
#pragma unroll
      for (int j = 0; j < KI; ++j) gload_lds16(kPtr[j], kd + kDstB[j]);
#pragma unroll
      for (int j = 0; j < KI; ++j) kPtr[j] += 32 * QKROW;
    }

    f32x4 s4[2];
    s4[0] = (f32x4){0.f, 0.f, 0.f, 0.f};
    s4[1] = (f32x4){0.f, 0.f, 0.f, 0.f};
    const unsigned char* kB = KsB + cur * KTILE;
    const int swz = lrow & 7;
    __builtin_amdgcn_s_setprio(1);
#pragma unroll
    for (int dc = 0; dc < NC; ++dc) {
#pragma unroll
      for (int t = 0; t < 2; ++t) {
        const bf16x8 kf = *reinterpret_cast<const bf16x8*>(
            kB + (t * 16 + lrow) * (S * 16) + (((dc * 4 + lgrp) ^ swz) * 16));
        s4[t] = __builtin_amdgcn_mfma_f32_16x16x32_bf16(kf, qf[dc], s4[t], 0, 0, 0);
      }
    }
    __builtin_amdgcn_s_setprio(0);

    float ps[8];
#pragma unroll
    for (int t = 0; t < 2; ++t)
#pragma unroll
      for (int r = 0; r < 4; ++r) ps[t * 4 + r] = s4[t][r] * scale;
    float pm = ps[0];
#pragma unroll
    for (int z = 1; z < 8; ++z) pm = fmaxf(pm, ps[z]);
    pm = fmaxf(pm, __shfl_xor(pm, 16));
    pm = fmaxf(pm, __shfl_xor(pm, 32));
    if (__any(pm > m_run + 8.0f)) {
      const float mn = fmaxf(m_run, pm);
      const float alpha = __expf(m_run - mn);
      m_run = mn; l_run *= alpha;
      float al4[4];
#pragma unroll
      for (int r = 0; r < 4; ++r) al4[r] = __shfl(alpha, lgrp * 4 + r);
#pragma unroll
      for (int t = 0; t < NT2; ++t) {
        if (t < ntiles) {
#pragma unroll
          for (int r = 0; r < 4; ++r) acc[t][r] *= al4[r];
        }
      }
    }
    float sum = 0.f;
#pragma unroll
    for (int z = 0; z < 8; ++z) { ps[z] = __expf(ps[z] - m_run); sum += ps[z]; }
    sum += __shfl_xor(sum, 16);
    sum += __shfl_xor(sum, 32);
    l_run += sum;

#pragma unroll
    for (int t = 0; t < 2; ++t) {
      uint2 w;
      w.x = pack2bf(ps[t * 4 + 0], ps[t * 4 + 1]);
      w.y = pack2bf(ps[t * 4 + 2], ps[t * 4 + 3]);
      *reinterpret_cast<uint2*>(PlW + lrow * 20 + 8 * t + 2 * lgrp) = w;
    }
    asm volatile("s_waitcnt lgkmcnt(0)" ::: "memory");
    __builtin_amdgcn_sched_barrier(0);
    const bf16x8 pa = *reinterpret_cast<const bf16x8*>(PlW + lrow * 20 + 4 * lgrp);

#pragma unroll
    for (int t0 = 0; t0 < NT2; t0 += 8) {
      bf16x8 vf[8];
#pragma unroll
      for (int j = 0; j < 8; ++j) {
        const int t = t0 + j;
        if (t < NT2 && t < ntiles)
          vf[j] = *reinterpret_cast<const bf16x8*>(vRow + (size_t)t * 32768 + kt);
      }
      __builtin_amdgcn_s_setprio(1);
#pragma unroll
      for (int j = 0; j < 8; ++j) {
        const int t = t0 + j;
        if (t < NT2 && t < ntiles)
          acc[t] = __builtin_amdgcn_mfma_f32_16x16x32_bf16(pa, vf[j], acc[t], 0, 0, 0);
      }
      __builtin_amdgcn_s_setprio(0);
    }
    __syncthreads();
  }

  float invl[4];
#pragma unroll
  for (int r = 0; r < 4; ++r) invl[r] = 1.0f / __shfl(l_run, lgrp * 4 + r);
#pragma unroll
  for (int t = 0; t < NT2; ++t) {
    if (t < ntiles) {
      const int col = t * 16 + lrow;
      if (col < d) {
#pragma unroll
        for (int r = 0; r < 4; ++r) {
          Op[(size_t)(b * 2048 + q0 + lgrp * 4 + r) * 512 + start + col] =
              f2bf(acc[t][r] * invl[r]);
        }
      }
    }
  }
  if (lgrp == 0) mlArr[mlBase + lrow] = make_float2(m_run, l_run);
}

__global__ __launch_bounds__(256, 3) void attn_fused(
    const unsigned short* __restrict__ qkpad,
    const unsigned short* __restrict__ Vt,
    unsigned short* __restrict__ O0,
    unsigned short* __restrict__ O1,
    float2* __restrict__ mlArr,
    const int* __restrict__ hdr,
    const int* __restrict__ sched)
{
  __shared__ __align__(16) unsigned char KsB[32768];
  __shared__ unsigned int Pl[4][16 * 20];

  const int sv = sched[blockIdx.x];
  if (sv < 0) return;
  const int h = sv & 15, b = (sv >> 4) & 15;
  const int qi = (sv >> 8) & 63;
  const int qb = qi & 31, kh = qi >> 5;
  const int d = hdr[h];
  const int nc = (d + 31) >> 5;
  if (nc > 8) return;
  const int start = hdr[8 + h];
  const int astart = hdr[16 + h];
  const int wave = threadIdx.x >> 6, lane = threadIdx.x & 63;
  const int q0 = qb * 64 + wave * 16;
  unsigned short* Op = kh ? O1 : O0;
  const int mlBase = (kh * 24 + h * 4 + b) * 2048 + q0;

  unsigned int* PlW = &Pl[wave][0];
  switch (nc) {
    case 1: attn_body<1>(qkpad, Vt, Op, mlArr, b, q0, d, start, astart, kh, mlBase, KsB, PlW, wave, lane); break;
    case 2: attn_body<2>(qkpad, Vt, Op, mlArr, b, q0, d, start, astart, kh, mlBase, KsB, PlW, wave, lane); break;
    case 3: attn_body<3>(qkpad, Vt, Op, mlArr, b, q0, d, start, astart, kh, mlBase, KsB, PlW, wave, lane); break;
    case 4: attn_body<4>(qkpad, Vt, Op, mlArr, b, q0, d, start, astart, kh, mlBase, KsB, PlW, wave, lane); break;
    case 5: attn_body<5>(qkpad, Vt, Op, mlArr, b, q0, d, start, astart, kh, mlBase, KsB, PlW, wave, lane); break;
    case 6: attn_body<6>(qkpad, Vt, Op, mlArr, b, q0, d, start, astart, kh, mlBase, KsB, PlW, wave, lane); break;
    case 7: attn_body<7>(qkpad, Vt, Op, mlArr, b, q0, d, start, astart, kh, mlBase, KsB, PlW, wave, lane); break;
    case 8: attn_body<8>(qkpad, Vt, Op, mlArr, b, q0, d, start, astart, kh, mlBase, KsB, PlW, wave, lane); break;
    default: break;
  }
}

// ---------------- merge v2: per-(b,h) blocks; ratio computed once per row ----------------
__global__ __launch_bounds__(256) void merge_kernel(
    const unsigned short* __restrict__ O0,
    const unsigned short* __restrict__ O1,
    const float2* __restrict__ mlArr,
    unsigned short* __restrict__ attnC,
    const int* __restrict__ hdr)
{
  const int sh = blockIdx.y;                 // 0..23
  const int h = sh >> 2, b = sh & 3;
  const int d = hdr[h];
  if (((d + 31) >> 5) > 8) return;           // fallback path owns these
  const int start = hdr[8 + h];
  const int q = blockIdx.x * 32 + (threadIdx.x >> 3);
  const int cg = threadIdx.x & 7;
  const float2 A = mlArr[(h * 4 + b) * 2048 + q];
  const float2 B = mlArr[(24 + h * 4 + b) * 2048 + q];
  const float M = fmaxf(A.x, B.x);
  const float a1 = __expf(A.x - M) * A.y;
  const float a2 = __expf(B.x - M) * B.y;
  const float inv = 1.0f / (a1 + a2);
  const float r1 = a1 * inv, r2 = a2 * inv;
  const size_t base = (size_t)(b * 2048 + q) * 512 + start;
  for (int c = cg; c < d; c += 8)
    attnC[base + c] = f2bf(r1 * bf2f(O0[base + c]) + r2 * bf2f(O1[base + c]));
}

// ---------------- direct fallback for nc>8 (d>256), normally all-exit ----------------
template<int NCLO, int NCHI>
__global__ __launch_bounds__(256, 2) void attn_kernel(
    const unsigned short* __restrict__ qkpad,
    const unsigned short* __restrict__ Vt,
    unsigned short* __restrict__ attnC,
    const int* __restrict__ hdr)
{
  const int h = blockIdx.y, b = blockIdx.z;
  const int d = hdr[h];
  const int nc = (d + 31) >> 5;
  if (nc <= NCLO || nc > NCHI) return;
  const int start = hdr[8 + h];
  const int astart = hdr[16 + h];
  const int wave = threadIdx.x >> 6;
  const int lane = threadIdx.x & 63;
  const int lrow = lane & 15, lgrp = lane >> 4;
  const int q0 = blockIdx.x * 64 + wave * 16;
  const int ntiles = (d + 15) >> 4;
  const float scale = 1.0f / sqrtf((float)d);

  __shared__ unsigned short Pl[2][4][16 * 32];

  bf16x8 qf[NCHI];
  {
    const size_t qbase = (size_t)(b * 2048 + q0 + lrow) * QKROW + astart;
#pragma unroll
    for (int dc = 0; dc < NCHI; ++dc) {
      if (dc < nc) {
        bf16x8 v = *reinterpret_cast<const bf16x8*>(&qkpad[qbase + dc * 32 + lgrp * 8]);
#pragma unroll
        for (int j = 0; j < 8; ++j)
          if (dc * 32 + lgrp * 8 + j >= d) v[j] = (__bf16)0.0f;
        qf[dc] = v;
      }
    }
  }

  f32x4 acc[2 * NCHI];
#pragma unroll
  for (int t = 0; t < 2 * NCHI; ++t) acc[t] = (f32x4){0.f, 0.f, 0.f, 0.f};
  float m_run[4] = {-1e30f, -1e30f, -1e30f, -1e30f};
  float l_run[4] = {0.f, 0.f, 0.f, 0.f};

  for (int kt = 0; kt < 2048; kt += 32) {
    f32x4 s0 = {0.f, 0.f, 0.f, 0.f}, s1 = {0.f, 0.f, 0.f, 0.f};
    const size_t kb0 = (size_t)(b * 2048 + kt + lrow) * QKROW + QKSTRIDE + astart;
    const size_t kb1 = kb0 + (size_t)16 * QKROW;
#pragma unroll
    for (int dc = 0; dc < NCHI; ++dc) {
      if (dc < nc) {
        bf16x8 k0 = *reinterpret_cast<const bf16x8*>(&qkpad[kb0 + dc * 32 + lgrp * 8]);
        bf16x8 k1 = *reinterpret_cast<const bf16x8*>(&qkpad[kb1 + dc * 32 + lgrp * 8]);
        s0 = __builtin_amdgcn_mfma_f32_16x16x32_bf16(qf[dc], k0, s0, 0, 0, 0);
        s1 = __builtin_amdgcn_mfma_f32_16x16x32_bf16(qf[dc], k1, s1, 0, 0, 0);
      }
    }
    float p0[4], p1[4], pmax[4];
#pragma unroll
    for (int r = 0; r < 4; ++r) {
      p0[r] = s0[r] * scale; p1[r] = s1[r] * scale;
      float mx = fmaxf(p0[r], p1[r]);
#pragma unroll
      for (int off = 1; off < 16; off <<= 1) mx = fmaxf(mx, __shfl_xor(mx, off));
      pmax[r] = mx;
    }
    bool need = false;
#pragma unroll
    for (int r = 0; r < 4; ++r) need = need || (pmax[r] > m_run[r] + 8.0f);
    if (__any(need)) {
#pragma unroll
      for (int r = 0; r < 4; ++r) {
        float mn = fmaxf(m_run[r], pmax[r]);
        float al = __expf(m_run[r] - mn);
        m_run[r] = mn; l_run[r] *= al;
#pragma unroll
        for (int t = 0; t < 2 * NCHI; ++t)
          if (t < ntiles) acc[t][r] *= al;
      }
    }
#pragma unroll
    for (int r = 0; r < 4; ++r) {
      p0[r] = __expf(p0[r] - m_run[r]);
      p1[r] = __expf(p1[r] - m_run[r]);
      float sm = p0[r] + p1[r];
#pragma unroll
      for (int off = 1; off < 16; off <<= 1) sm += __shfl_xor(sm, off);
      l_run[r] += sm;
    }
    const int pb = (kt >> 5) & 1;
    unsigned short* P = &Pl[pb][wave][0];
#pragma unroll
    for (int r = 0; r < 4; ++r) {
      P[(lgrp * 4 + r) * 32 + lrow] = f2bf(p0[r]);
      P[(lgrp * 4 + r) * 32 + 16 + lrow] = f2bf(p1[r]);
    }
    asm volatile("s_waitcnt lgkmcnt(0)" ::: "memory");
    bf16x8 pf = *reinterpret_cast<const bf16x8*>(&P[lrow * 32 + lgrp * 8]);
    const size_t vbase = (size_t)(b * VTPAD + start) * 2048 + kt + lgrp * 8;
#pragma unroll
    for (int t = 0; t < 2 * NCHI; ++t) {
      if (t < ntiles) {
        bf16x8 vf = *reinterpret_cast<const bf16x8*>(&Vt[vbase + (size_t)(t * 16 + lrow) * 2048]);
        acc[t] = __builtin_amdgcn_mfma_f32_16x16x32_bf16(pf, vf, acc[t], 0, 0, 0);
      }
    }
  }

  float inv[4];
#pragma unroll
  for (int r = 0; r < 4; ++r) inv[r] = 1.0f / l_run[r];
#pragma unroll
  for (int t = 0; t < 2 * NCHI; ++t) {
    if (t < ntiles) {
      int col = t * 16 + lrow;
      if (col < d) {
#pragma unroll
        for (int r = 0; r < 4; ++r) {
          attnC[(size_t)(b * 2048 + q0 + lgrp * 4 + r) * 512 + start + col] =
              f2bf(acc[t][r] * inv[r]);
        }
      }
    }
  }
}

// ---------------- launch ----------------
extern "C" void kernel_launch(void* const* d_in, const int* in_sizes, int n_in,
                              void* d_out, int out_size, void* d_ws, size_t ws_size,
                              hipStream_t stream) {
  const float* query  = (const float*)d_in[0];
  const float* logits = (const float*)d_in[1];
  const float* w_qkv  = (const float*)d_in[2];
  const float* b_qkv  = (const float*)d_in[3];
  const float* w_out  = (const float*)d_in[4];
  const float* b_out  = (const float*)d_in[5];
  float* out = (float*)d_out;

  char* p = (char*)d_ws;
  size_t off = 0;
  auto alloc = [&](size_t bytes) {
    void* r = p + off; off += (bytes + 255) & ~(size_t)255; return r;
  };
  int* hdr              = (int*)alloc(1024);
  int* cmap             = (int*)alloc(2048 * 4);
  int* sched            = (int*)alloc(1536 * 4);
  unsigned short* qbf   = (unsigned short*)alloc((size_t)8192 * 512 * 2);   // reused as O0
  unsigned short* wqkvT = (unsigned short*)alloc((size_t)1536 * 512 * 2);
  unsigned short* woutT = (unsigned short*)alloc((size_t)512 * 512 * 2);
  unsigned short* qkpad = (unsigned short*)alloc((size_t)8192 * QKROW * 2 + 4096);
  unsigned short* vbuf  = (unsigned short*)alloc((size_t)8192 * 512 * 2);   // reused as O1
  unsigned short* Vt    = (unsigned short*)alloc((size_t)4 * VTPAD * 2048 * 2 + 4096);
  unsigned short* attnC = (unsigned short*)alloc((size_t)8192 * 512 * 2);
  float2* mlArr         = (float2*)alloc((size_t)2 * 24 * 2048 * 8);
  (void)ws_size; (void)in_sizes; (void)n_in; (void)out_size;

  prep_kernel<<<1, 64, 0, stream>>>(logits, hdr, cmap, sched, out + 4194304);
  conv_bf16_kernel<<<4096, 256, 0, stream>>>(query, qbf, 8192 * 512 / 4);
  convWT2_kernel<<<dim3(8, 24, 2), 256, 0, stream>>>(w_qkv, w_out, wqkvT, woutT);
  gemm_bt<1><<<dim3(12, 64), 256, 0, stream>>>(qbf, wqkvT, b_qkv, nullptr, qkpad, Vt, cmap, 1536, 512);
  // qbf/vbuf dead from here -> reuse as split-K partial buffers O0/O1 (transV fused into gemm)
  attn_fused<<<dim3(1536, 1, 1), 256, 0, stream>>>(qkpad, Vt, qbf, vbuf, mlArr, hdr, sched);
  attn_kernel<8, 15><<<dim3(32, 6, 4), 256, 0, stream>>>(qkpad, Vt, attnC, hdr);
  merge_kernel<<<dim3(64, 24), 256, 0, stream>>>(qbf, vbuf, mlArr, attnC, hdr);
  gemm_bt<0><<<dim3(4, 64), 256, 0, stream>>>(attnC, woutT, b_out, out, nullptr, nullptr, nullptr, 512, 512);
}

// Round 17
// 281.569 us; speedup vs baseline: 1.0569x; 1.0131x over previous
//
#include <hip/hip_runtime.h>
#include <hip/hip_bf16.h>
#include <cstdint>

typedef __attribute__((ext_vector_type(8))) __bf16 bf16x8;
typedef __attribute__((ext_vector_type(8))) unsigned short u16x8;
typedef __attribute__((ext_vector_type(4))) float f32x4;

#define QKSTRIDE 640
#define QKROW 1280
#define VTPAD 528

static __device__ __forceinline__ unsigned short f2bf(float f) {
  __hip_bfloat16 h = __float2bfloat16(f);
  return *reinterpret_cast<unsigned short*>(&h);
}
static __device__ __forceinline__ float bf2f(unsigned short u) {
  union { unsigned v; float f; } c; c.v = ((unsigned)u) << 16; return c.f;
}
static __device__ __forceinline__ unsigned pack2bf(float a, float b) {
  return (unsigned)f2bf(a) | ((unsigned)f2bf(b) << 16);
}

static __device__ __forceinline__ void gload_lds16(const void* g, void* lds) {
  __builtin_amdgcn_global_load_lds(
      (const __attribute__((address_space(1))) unsigned int*)g,
      (__attribute__((address_space(3))) unsigned int*)lds, 16, 0, 0);
}

// ---------------- prep: head dims, loss, column maps, split-K schedule (parallel; R9) ----------------
__global__ void prep_kernel(const float* __restrict__ logits, int* __restrict__ hdr,
                            int* __restrict__ cmap, int* __restrict__ sched,
                            float* __restrict__ loss_out) {
  __shared__ int sh_starts[8], sh_astarts[8];
  __shared__ int sh_ax[24], sh_apos[24], sh_ah[24], sh_ab[24];
  const int tid = threadIdx.x;
  if (blockIdx.x != 0) return;

  if (tid == 0) {
    float l[6]; float mx = -1e30f;
    for (int i = 0; i < 6; ++i) { l[i] = logits[i]; mx = fmaxf(mx, l[i]); }
    float e[6]; float s = 0.f;
    for (int i = 0; i < 6; ++i) { e[i] = expf(l[i] - mx); s += e[i]; }
    float hdf[6]; float sumh = 0.f;
    for (int i = 0; i < 6; ++i) { hdf[i] = 8.0f + (e[i] / s) * 464.0f; sumh += hdf[i]; }
    int hdi[6]; float res[6]; int isum = 0;
    for (int i = 0; i < 6; ++i) {
      float fl = floorf(hdf[i]);
      hdi[i] = (int)fl; res[i] = hdf[i] - fl; isum += hdi[i];
    }
    int diff = 512 - isum;
    bool used[6] = {false, false, false, false, false, false};
    if (diff > 0) {
      for (int t = 0; t < diff; ++t) {
        int best = -1; float bv = -1e30f;
        for (int i = 0; i < 6; ++i) if (!used[i] && res[i] > bv) { bv = res[i]; best = i; }
        used[best] = true; hdi[best] += 1;
      }
    } else if (diff < 0) {
      for (int t = 0; t < -diff; ++t) {
        int best = -1; float bv = 1e30f;
        for (int i = 0; i < 6; ++i) if (!used[i] && res[i] < bv) { bv = res[i]; best = i; }
        used[best] = true; hdi[best] -= 1;
      }
    }
    { int st = 0, ast = 0;
      for (int i = 0; i < 6; ++i) {
        sh_starts[i] = st; sh_astarts[i] = ast;
        hdr[i] = hdi[i]; hdr[8 + i] = st; hdr[16 + i] = ast;
        st += hdi[i]; ast += (hdi[i] + 7) & ~7;
      }
      sh_starts[6] = st; sh_starts[7] = st;
    }
    // LPT: 24 (h,b) sets, 64 blocks each, 8 XCD bins cap 192
    int csth[6];
    for (int i = 0; i < 6; ++i) {
      int ncl = (hdi[i] + 31) / 32;
      int ntl = (hdi[i] + 15) / 16;
      csth[i] = 4 * ncl + 2 * ntl + 8;
    }
    int ord[6] = {0, 1, 2, 3, 4, 5};
    for (int a = 0; a < 6; ++a)
      for (int c = a + 1; c < 6; ++c)
        if (csth[ord[c]] > csth[ord[a]]) { int t = ord[a]; ord[a] = ord[c]; ord[c] = t; }
    int binload[8], bincnt[8];
    for (int x = 0; x < 8; ++x) { binload[x] = 0; bincnt[x] = 0; }
    int na = 0;
    for (int a = 0; a < 6; ++a) {
      const int hh = ord[a];
      for (int bb = 0; bb < 4; ++bb) {
        int best = -1;
        for (int x = 0; x < 8; ++x)
          if (bincnt[x] + 64 <= 192 && (best < 0 || binload[x] < binload[best])) best = x;
        if (best < 0) best = 0;
        sh_ax[na] = best; sh_apos[na] = bincnt[best];
        sh_ah[na] = hh; sh_ab[na] = bb; ++na;
        bincnt[best] += 64;
        binload[best] += csth[hh];
      }
    }
    // loss
    float dv = sumh - 512.0f;
    float floss = dv * dv;
    float rsum = 0.f;
    for (int i = 0; i < 6; ++i) rsum += fmaxf(8.0f - hdf[i], 0.0f);
    floss += rsum / 6.0f;
    float il = 0.f;
    for (int i = 0; i < 6; ++i) { float dd = hdf[i] - (float)hdi[i]; il += dd * dd; }
    il /= 6.0f;
    loss_out[0] = floss + 0.5f * il;
  }
  __syncthreads();

  for (int col = tid; col < 512; col += 64) {
    int hh = 5;
    for (int i = 0; i < 5; ++i) if (col < sh_starts[i + 1]) { hh = i; break; }
    int qc = sh_astarts[hh] + (col - sh_starts[hh]);
    cmap[col] = qc;
    cmap[512 + col] = QKSTRIDE + qc;
    cmap[1024 + col] = 4096 + col;
    cmap[1536 + col] = hh;
  }
  for (int e = tid; e < 1536; e += 64) sched[e] = -1;
  __syncthreads();
  for (int e = tid; e < 24 * 64; e += 64) {
    const int a = e >> 6, qi = e & 63;
    sched[sh_ax[a] + 8 * (sh_apos[a] + qi)] = sh_ah[a] | (sh_ab[a] << 4) | (qi << 8);
  }
}

// ---------------- converters ----------------
__global__ void conv_bf16_kernel(const float* __restrict__ x, unsigned short* __restrict__ y, int n4) {
  int i = blockIdx.x * blockDim.x + threadIdx.x;
  if (i >= n4) return;
  float4 v = reinterpret_cast<const float4*>(x)[i];
  union { unsigned short u[4]; uint2 q; } o;
  o.u[0] = f2bf(v.x); o.u[1] = f2bf(v.y); o.u[2] = f2bf(v.z); o.u[3] = f2bf(v.w);
  reinterpret_cast<uint2*>(y)[i] = o.q;
}

// coalesced LDS-tiled transpose: WT[n][k] = bf16(W[k][n]); z=0: w_qkv (N=1536), z=1: w_out (N=512)
__global__ void convWT2_kernel(const float* __restrict__ Wqkv, const float* __restrict__ Wout,
                               unsigned short* __restrict__ wqkvT, unsigned short* __restrict__ woutT) {
  __shared__ float tile[64][65];
  const int mz = blockIdx.z;
  if (mz && blockIdx.y >= 8) return;
  const int N = mz ? 512 : 1536;
  const float* W = mz ? Wout : Wqkv;
  unsigned short* WT = mz ? woutT : wqkvT;
  const int k0 = blockIdx.x * 64, n0 = blockIdx.y * 64;
  const int t = threadIdx.x;
  {
    const int c = (t & 15) * 4;
#pragma unroll
    for (int rp = 0; rp < 4; ++rp) {
      const int r = rp * 16 + (t >> 4);
      float4 v = *reinterpret_cast<const float4*>(&W[(size_t)(k0 + r) * N + n0 + c]);
      tile[r][c] = v.x; tile[r][c + 1] = v.y; tile[r][c + 2] = v.z; tile[r][c + 3] = v.w;
    }
  }
  __syncthreads();
  {
    const int n = t >> 2, kc = (t & 3) * 16;
    unsigned short outv[16];
#pragma unroll
    for (int j = 0; j < 16; ++j) outv[j] = f2bf(tile[kc + j][n]);
    unsigned short* dst = &WT[(size_t)(n0 + n) * 512 + k0 + kc];
    *reinterpret_cast<u16x8*>(dst) = *reinterpret_cast<u16x8*>(&outv[0]);
    *reinterpret_cast<u16x8*>(dst + 8) = *reinterpret_cast<u16x8*>(&outv[8]);
  }
}

// ---------------- GEMM: C[M][N] = A[M][K](bf16) @ Bt[N][K]^T + bias ----------------
// MODE 0: f32 out. MODE 1: bf16 scatter; Q/K via cmap to qkpad, V written TRANSPOSED
// into Vt (packed 4x bf16 per store: per-thread rows are 4 consecutive t).
template<int MODE>
__global__ __launch_bounds__(256, 2) void gemm_bt(
    const unsigned short* __restrict__ A,
    const unsigned short* __restrict__ Bt,
    const float* __restrict__ bias,
    float* __restrict__ Cf,
    unsigned short* __restrict__ qkpad,
    unsigned short* __restrict__ VtOut,
    const int* __restrict__ cmap,
    int N, int K)
{
  __shared__ unsigned short As[128 * 32];
  __shared__ unsigned short Bs[128 * 32];
  const int tid = threadIdx.x;
  const int wave = tid >> 6, lane = tid & 63;
  const int lrow = lane & 15, lgrp = lane >> 4;
  const int wm = wave >> 1, wn = wave & 1;
  const int brow = blockIdx.y * 128;
  const int bcol = blockIdx.x * 128;

  f32x4 acc[4][4];
#pragma unroll
  for (int m = 0; m < 4; ++m)
#pragma unroll
    for (int n = 0; n < 4; ++n) acc[m][n] = (f32x4){0.f, 0.f, 0.f, 0.f};

  const int sig0 = wave * 128 + lane;
  for (int kb = 0; kb < K; kb += 32) {
    __syncthreads();
#pragma unroll
    for (int it = 0; it < 2; ++it) {
      const int sigma = sig0 + it * 64;
      const int r = sigma >> 2, sp = sigma & 3;
      const int sl = sp ^ ((r >> 1) & 3);
      gload_lds16(&A[(size_t)(brow + r) * K + kb + sl * 8], &As[sigma * 8]);
    }
#pragma unroll
    for (int it = 0; it < 2; ++it) {
      const int sigma = sig0 + it * 64;
      const int r = sigma >> 2, sp = sigma & 3;
      const int sl = sp ^ ((r >> 1) & 3);
      gload_lds16(&Bt[(size_t)(bcol + r) * K + kb + sl * 8], &Bs[sigma * 8]);
    }
    __syncthreads();
    const int sub = (lgrp ^ ((lrow >> 1) & 3)) * 8;
    bf16x8 aF[4], bF[4];
#pragma unroll
    for (int m = 0; m < 4; ++m)
      aF[m] = *reinterpret_cast<const bf16x8*>(&As[(wm * 64 + m * 16 + lrow) * 32 + sub]);
#pragma unroll
    for (int n = 0; n < 4; ++n)
      bF[n] = *reinterpret_cast<const bf16x8*>(&Bs[(wn * 64 + n * 16 + lrow) * 32 + sub]);
#pragma unroll
    for (int m = 0; m < 4; ++m)
#pragma unroll
      for (int n = 0; n < 4; ++n)
        acc[m][n] = __builtin_amdgcn_mfma_f32_16x16x32_bf16(aF[m], bF[n], acc[m][n], 0, 0, 0);
  }

#pragma unroll
  for (int n = 0; n < 4; ++n) {
    const int col = bcol + wn * 64 + n * 16 + lrow;
    const float bv = bias[col];
    int mc = 0;
    if (MODE == 1) mc = cmap[col];
#pragma unroll
    for (int m = 0; m < 4; ++m) {
      if (MODE == 0) {
#pragma unroll
        for (int r = 0; r < 4; ++r) {
          const int row = brow + wm * 64 + m * 16 + lgrp * 4 + r;
          Cf[(size_t)row * N + col] = acc[m][n][r] + bv;
        }
      } else if (mc < 4096) {
#pragma unroll
        for (int r = 0; r < 4; ++r) {
          const int row = brow + wm * 64 + m * 16 + lgrp * 4 + r;
          qkpad[(size_t)row * QKROW + mc] = f2bf(acc[m][n][r] + bv);
        }
      } else {
        // V: transpose on the fly. Rows are 4 consecutive t -> one 8B packed store.
        const int t0g = brow + wm * 64 + m * 16 + lgrp * 4;
        const int b = t0g >> 11, t0 = t0g & 2047;
        uint2 w;
        w.x = pack2bf(acc[m][n][0] + bv, acc[m][n][1] + bv);
        w.y = pack2bf(acc[m][n][2] + bv, acc[m][n][3] + bv);
        *reinterpret_cast<uint2*>(&VtOut[(size_t)(b * VTPAD + (mc - 4096)) * 2048 + t0]) = w;
      }
    }
  }
}

// ---------------- split-K flash attention (R9 body; V batch-0 hoisted for NC<=6) ----------------
template<int NC>
static __device__ __forceinline__ void attn_body(
    const unsigned short* __restrict__ qkpad,
    const unsigned short* __restrict__ Vt,
    unsigned short* __restrict__ Op,
    float2* __restrict__ mlArr,
    int b, int q0, int d, int start, int astart, int kh, int mlBase,
    unsigned char* KsB, unsigned int* PlW,
    int wave, int lane)
{
  constexpr int S = (4 * NC + 7) & ~7;
  constexpr int NT2 = 2 * NC;
  constexpr int NB0 = (NT2 < 8) ? NT2 : 8;
  constexpr bool HOIST = (NC <= 6);       // register headroom check: worst arm ~139 < 170 cap
  constexpr int KI = S / 8;
  constexpr int KTILE = 32 * S * 16;
  const int ntiles = (d + 15) >> 4;
  const int lrow = lane & 15, lgrp = lane >> 4;
  const float scale = 1.0f / sqrtf((float)d);

  bf16x8 qf[NC];
  {
    const unsigned short* qp = qkpad + (size_t)(b * 2048 + q0 + lrow) * QKROW + astart + lgrp * 8;
#pragma unroll
    for (int dc = 0; dc < NC; ++dc) {
      bf16x8 v = *reinterpret_cast<const bf16x8*>(qp + dc * 32);
#pragma unroll
      for (int j = 0; j < 8; ++j)
        if (dc * 32 + lgrp * 8 + j >= d) v[j] = (__bf16)0.0f;
      qf[dc] = v;
    }
  }

  const unsigned short* kPtr[KI];
  int kDstB[KI];
#pragma unroll
  for (int j = 0; j < KI; ++j) {
    const int g = (wave * KI + j) * 64 + lane;
    const int r = g / S, pp = g - r * S;
    const int sp = pp ^ (r & 7);
    kPtr[j] = qkpad + (size_t)(b * 2048 + kh * 1024 + r) * QKROW + QKSTRIDE + astart + sp * 8;
    kDstB[j] = g * 16;
  }

  const unsigned short* vRow = Vt + (size_t)(b * VTPAD + start + lrow) * 2048 + kh * 1024 + lgrp * 8;

  f32x4 acc[NT2];
#pragma unroll
  for (int t = 0; t < NT2; ++t) acc[t] = (f32x4){0.f, 0.f, 0.f, 0.f};
  float m_run = -1e30f, l_run = 0.f;

#pragma unroll
  for (int j = 0; j < KI; ++j) gload_lds16(kPtr[j], KsB + kDstB[j]);
#pragma unroll
  for (int j = 0; j < KI; ++j) kPtr[j] += 32 * QKROW;
  __syncthreads();

  for (int i = 0; i < 32; ++i) {
    const int kt = i << 5;
    const int cur = i & 1;
    if (i < 31) {
      unsigned char* kd = KsB + (cur ^ 1) * KTILE;
#pragma unroll
      for (int j = 0; j < KI; ++j) gload_lds16(kPtr[j], kd + kDstB[j]);
#pragma unroll
      for (int j = 0; j < KI; ++j) kPtr[j] += 32 * QKROW;
    }

    // ---- V batch-0 hoist (NC<=6): L2 latency lands under QK + softmax ----
    bf16x8 vf0[NB0];
    if constexpr (HOIST) {
#pragma unroll
      for (int j = 0; j < NB0; ++j)
        if (j < ntiles)
          vf0[j] = *reinterpret_cast<const bf16x8*>(vRow + (size_t)j * 32768 + kt);
    }

    f32x4 s4[2];
    s4[0] = (f32x4){0.f, 0.f, 0.f, 0.f};
    s4[1] = (f32x4){0.f, 0.f, 0.f, 0.f};
    const unsigned char* kB = KsB + cur * KTILE;
    const int swz = lrow & 7;
    __builtin_amdgcn_s_setprio(1);
#pragma unroll
    for (int dc = 0; dc < NC; ++dc) {
#pragma unroll
      for (int t = 0; t < 2; ++t) {
        const bf16x8 kf = *reinterpret_cast<const bf16x8*>(
            kB + (t * 16 + lrow) * (S * 16) + (((dc * 4 + lgrp) ^ swz) * 16));
        s4[t] = __builtin_amdgcn_mfma_f32_16x16x32_bf16(kf, qf[dc], s4[t], 0, 0, 0);
      }
    }
    __builtin_amdgcn_s_setprio(0);

    float ps[8];
#pragma unroll
    for (int t = 0; t < 2; ++t)
#pragma unroll
      for (int r = 0; r < 4; ++r) ps[t * 4 + r] = s4[t][r] * scale;
    float pm = ps[0];
#pragma unroll
    for (int z = 1; z < 8; ++z) pm = fmaxf(pm, ps[z]);
    pm = fmaxf(pm, __shfl_xor(pm, 16));
    pm = fmaxf(pm, __shfl_xor(pm, 32));
    if (__any(pm > m_run + 8.0f)) {
      const float mn = fmaxf(m_run, pm);
      const float alpha = __expf(m_run - mn);
      m_run = mn; l_run *= alpha;
      float al4[4];
#pragma unroll
      for (int r = 0; r < 4; ++r) al4[r] = __shfl(alpha, lgrp * 4 + r);
#pragma unroll
      for (int t = 0; t < NT2; ++t) {
        if (t < ntiles) {
#pragma unroll
          for (int r = 0; r < 4; ++r) acc[t][r] *= al4[r];
        }
      }
    }
    float sum = 0.f;
#pragma unroll
    for (int z = 0; z < 8; ++z) { ps[z] = __expf(ps[z] - m_run); sum += ps[z]; }
    sum += __shfl_xor(sum, 16);
    sum += __shfl_xor(sum, 32);
    l_run += sum;

#pragma unroll
    for (int t = 0; t < 2; ++t) {
      uint2 w;
      w.x = pack2bf(ps[t * 4 + 0], ps[t * 4 + 1]);
      w.y = pack2bf(ps[t * 4 + 2], ps[t * 4 + 3]);
      *reinterpret_cast<uint2*>(PlW + lrow * 20 + 8 * t + 2 * lgrp) = w;
    }
    asm volatile("s_waitcnt lgkmcnt(0)" ::: "memory");
    __builtin_amdgcn_sched_barrier(0);
    const bf16x8 pa = *reinterpret_cast<const bf16x8*>(PlW + lrow * 20 + 4 * lgrp);

    if constexpr (HOIST) {
      // ---- PV batch-0 (preloaded) ----
      __builtin_amdgcn_s_setprio(1);
#pragma unroll
      for (int j = 0; j < NB0; ++j)
        if (j < ntiles)
          acc[j] = __builtin_amdgcn_mfma_f32_16x16x32_bf16(pa, vf0[j], acc[j], 0, 0, 0);
      __builtin_amdgcn_s_setprio(0);
      if constexpr (NT2 > 8) {
        bf16x8 vf1[NT2 - 8];
#pragma unroll
        for (int j = 0; j < NT2 - 8; ++j) {
          const int t = 8 + j;
          if (t < ntiles)
            vf1[j] = *reinterpret_cast<const bf16x8*>(vRow + (size_t)t * 32768 + kt);
        }
        __builtin_amdgcn_s_setprio(1);
#pragma unroll
        for (int j = 0; j < NT2 - 8; ++j) {
          const int t = 8 + j;
          if (t < ntiles)
            acc[t] = __builtin_amdgcn_mfma_f32_16x16x32_bf16(pa, vf1[j], acc[t], 0, 0, 0);
        }
        __builtin_amdgcn_s_setprio(0);
      }
    } else {
      // ---- original batched PV (NC=7,8: registers too tight to hoist) ----
#pragma unroll
      for (int t0 = 0; t0 < NT2; t0 += 8) {
        bf16x8 vf[8];
#pragma unroll
        for (int j = 0; j < 8; ++j) {
          const int t = t0 + j;
          if (t < NT2 && t < ntiles)
            vf[j] = *reinterpret_cast<const bf16x8*>(vRow + (size_t)t * 32768 + kt);
        }
        __builtin_amdgcn_s_setprio(1);
#pragma unroll
        for (int j = 0; j < 8; ++j) {
          const int t = t0 + j;
          if (t < NT2 && t < ntiles)
            acc[t] = __builtin_amdgcn_mfma_f32_16x16x32_bf16(pa, vf[j], acc[t], 0, 0, 0);
        }
        __builtin_amdgcn_s_setprio(0);
      }
    }
    __syncthreads();
  }

  float invl[4];
#pragma unroll
  for (int r = 0; r < 4; ++r) invl[r] = 1.0f / __shfl(l_run, lgrp * 4 + r);
#pragma unroll
  for (int t = 0; t < NT2; ++t) {
    if (t < ntiles) {
      const int col = t * 16 + lrow;
      if (col < d) {
#pragma unroll
        for (int r = 0; r < 4; ++r) {
          Op[(size_t)(b * 2048 + q0 + lgrp * 4 + r) * 512 + start + col] =
              f2bf(acc[t][r] * invl[r]);
        }
      }
    }
  }
  if (lgrp == 0) mlArr[mlBase + lrow] = make_float2(m_run, l_run);
}

__global__ __launch_bounds__(256, 3) void attn_fused(
    const unsigned short* __restrict__ qkpad,
    const unsigned short* __restrict__ Vt,
    unsigned short* __restrict__ O0,
    unsigned short* __restrict__ O1,
    float2* __restrict__ mlArr,
    const int* __restrict__ hdr,
    const int* __restrict__ sched)
{
  __shared__ __align__(16) unsigned char KsB[32768];
  __shared__ unsigned int Pl[4][16 * 20];

  const int sv = sched[blockIdx.x];
  if (sv < 0) return;
  const int h = sv & 15, b = (sv >> 4) & 15;
  const int qi = (sv >> 8) & 63;
  const int qb = qi & 31, kh = qi >> 5;
  const int d = hdr[h];
  const int nc = (d + 31) >> 5;
  if (nc > 8) return;
  const int start = hdr[8 + h];
  const int astart = hdr[16 + h];
  const int wave = threadIdx.x >> 6, lane = threadIdx.x & 63;
  const int q0 = qb * 64 + wave * 16;
  unsigned short* Op = kh ? O1 : O0;
  const int mlBase = (kh * 24 + h * 4 + b) * 2048 + q0;

  unsigned int* PlW = &Pl[wave][0];
  switch (nc) {
    case 1: attn_body<1>(qkpad, Vt, Op, mlArr, b, q0, d, start, astart, kh, mlBase, KsB, PlW, wave, lane); break;
    case 2: attn_body<2>(qkpad, Vt, Op, mlArr, b, q0, d, start, astart, kh, mlBase, KsB, PlW, wave, lane); break;
    case 3: attn_body<3>(qkpad, Vt, Op, mlArr, b, q0, d, start, astart, kh, mlBase, KsB, PlW, wave, lane); break;
    case 4: attn_body<4>(qkpad, Vt, Op, mlArr, b, q0, d, start, astart, kh, mlBase, KsB, PlW, wave, lane); break;
    case 5: attn_body<5>(qkpad, Vt, Op, mlArr, b, q0, d, start, astart, kh, mlBase, KsB, PlW, wave, lane); break;
    case 6: attn_body<6>(qkpad, Vt, Op, mlArr, b, q0, d, start, astart, kh, mlBase, KsB, PlW, wave, lane); break;
    case 7: attn_body<7>(qkpad, Vt, Op, mlArr, b, q0, d, start, astart, kh, mlBase, KsB, PlW, wave, lane); break;
    case 8: attn_body<8>(qkpad, Vt, Op, mlArr, b, q0, d, start, astart, kh, mlBase, KsB, PlW, wave, lane); break;
    default: break;
  }
}

// ---------------- merge v2: per-(b,h) blocks; ratio computed once per row ----------------
__global__ __launch_bounds__(256) void merge_kernel(
    const unsigned short* __restrict__ O0,
    const unsigned short* __restrict__ O1,
    const float2* __restrict__ mlArr,
    unsigned short* __restrict__ attnC,
    const int* __restrict__ hdr)
{
  const int sh = blockIdx.y;                 // 0..23
  const int h = sh >> 2, b = sh & 3;
  const int d = hdr[h];
  if (((d + 31) >> 5) > 8) return;
  const int start = hdr[8 + h];
  const int q = blockIdx.x * 32 + (threadIdx.x >> 3);
  const int cg = threadIdx.x & 7;
  const float2 A = mlArr[(h * 4 + b) * 2048 + q];
  const float2 B = mlArr[(24 + h * 4 + b) * 2048 + q];
  const float M = fmaxf(A.x, B.x);
  const float a1 = __expf(A.x - M) * A.y;
  const float a2 = __expf(B.x - M) * B.y;
  const float inv = 1.0f / (a1 + a2);
  const float r1 = a1 * inv, r2 = a2 * inv;
  const size_t base = (size_t)(b * 2048 + q) * 512 + start;
  for (int c = cg; c < d; c += 8)
    attnC[base + c] = f2bf(r1 * bf2f(O0[base + c]) + r2 * bf2f(O1[base + c]));
}

// ---------------- launch ----------------
extern "C" void kernel_launch(void* const* d_in, const int* in_sizes, int n_in,
                              void* d_out, int out_size, void* d_ws, size_t ws_size,
                              hipStream_t stream) {
  const float* query  = (const float*)d_in[0];
  const float* logits = (const float*)d_in[1];
  const float* w_qkv  = (const float*)d_in[2];
  const float* b_qkv  = (const float*)d_in[3];
  const float* w_out  = (const float*)d_in[4];
  const float* b_out  = (const float*)d_in[5];
  float* out = (float*)d_out;

  char* p = (char*)d_ws;
  size_t off = 0;
  auto alloc = [&](size_t bytes) {
    void* r = p + off; off += (bytes + 255) & ~(size_t)255; return r;
  };
  int* hdr              = (int*)alloc(1024);
  int* cmap             = (int*)alloc(2048 * 4);
  int* sched            = (int*)alloc(1536 * 4);
  unsigned short* qbf   = (unsigned short*)alloc((size_t)8192 * 512 * 2);   // reused as O0
  unsigned short* wqkvT = (unsigned short*)alloc((size_t)1536 * 512 * 2);
  unsigned short* woutT = (unsigned short*)alloc((size_t)512 * 512 * 2);
  unsigned short* qkpad = (unsigned short*)alloc((size_t)8192 * QKROW * 2 + 4096);
  unsigned short* vbuf  = (unsigned short*)alloc((size_t)8192 * 512 * 2);   // reused as O1
  unsigned short* Vt    = (unsigned short*)alloc((size_t)4 * VTPAD * 2048 * 2 + 4096);
  unsigned short* attnC = (unsigned short*)alloc((size_t)8192 * 512 * 2);
  float2* mlArr         = (float2*)alloc((size_t)2 * 24 * 2048 * 8);
  (void)ws_size; (void)in_sizes; (void)n_in; (void)out_size;

  prep_kernel<<<1, 64, 0, stream>>>(logits, hdr, cmap, sched, out + 4194304);
  conv_bf16_kernel<<<4096, 256, 0, stream>>>(query, qbf, 8192 * 512 / 4);
  convWT2_kernel<<<dim3(8, 24, 2), 256, 0, stream>>>(w_qkv, w_out, wqkvT, woutT);
  gemm_bt<1><<<dim3(12, 64), 256, 0, stream>>>(qbf, wqkvT, b_qkv, nullptr, qkpad, Vt, cmap, 1536, 512);
  // qbf/vbuf dead from here -> reuse as split-K partial buffers O0/O1 (transV fused into gemm)
  attn_fused<<<dim3(1536, 1, 1), 256, 0, stream>>>(qkpad, Vt, qbf, vbuf, mlArr, hdr, sched);
  merge_kernel<<<dim3(64, 24), 256, 0, stream>>>(qbf, vbuf, mlArr, attnC, hdr);
  gemm_bt<0><<<dim3(4, 64), 256, 0, stream>>>(attnC, woutT, b_out, out, nullptr, nullptr, nullptr, 512, 512);
}

// Round 18
// 279.792 us; speedup vs baseline: 1.0636x; 1.0064x over previous
//
#include <hip/hip_runtime.h>
#include <hip/hip_bf16.h>
#include <cstdint>

typedef __attribute__((ext_vector_type(8))) __bf16 bf16x8;
typedef __attribute__((ext_vector_type(8))) unsigned short u16x8;
typedef __attribute__((ext_vector_type(4))) float f32x4;

#define QKSTRIDE 640
#define QKROW 1280
#define VTPAD 528

static __device__ __forceinline__ unsigned short f2bf(float f) {
  __hip_bfloat16 h = __float2bfloat16(f);
  return *reinterpret_cast<unsigned short*>(&h);
}
static __device__ __forceinline__ float bf2f(unsigned short u) {
  union { unsigned v; float f; } c; c.v = ((unsigned)u) << 16; return c.f;
}
static __device__ __forceinline__ unsigned pack2bf(float a, float b) {
  return (unsigned)f2bf(a) | ((unsigned)f2bf(b) << 16);
}

static __device__ __forceinline__ void gload_lds16(const void* g, void* lds) {
  __builtin_amdgcn_global_load_lds(
      (const __attribute__((address_space(1))) unsigned int*)g,
      (__attribute__((address_space(3))) unsigned int*)lds, 16, 0, 0);
}

// ---------------- prep: head dims, loss, column maps, split-K schedule (parallel; R9) ----------------
__global__ void prep_kernel(const float* __restrict__ logits, int* __restrict__ hdr,
                            int* __restrict__ cmap, int* __restrict__ sched,
                            float* __restrict__ loss_out) {
  __shared__ int sh_starts[8], sh_astarts[8];
  __shared__ int sh_ax[24], sh_apos[24], sh_ah[24], sh_ab[24];
  const int tid = threadIdx.x;
  if (blockIdx.x != 0) return;

  if (tid == 0) {
    float l[6]; float mx = -1e30f;
    for (int i = 0; i < 6; ++i) { l[i] = logits[i]; mx = fmaxf(mx, l[i]); }
    float e[6]; float s = 0.f;
    for (int i = 0; i < 6; ++i) { e[i] = expf(l[i] - mx); s += e[i]; }
    float hdf[6]; float sumh = 0.f;
    for (int i = 0; i < 6; ++i) { hdf[i] = 8.0f + (e[i] / s) * 464.0f; sumh += hdf[i]; }
    int hdi[6]; float res[6]; int isum = 0;
    for (int i = 0; i < 6; ++i) {
      float fl = floorf(hdf[i]);
      hdi[i] = (int)fl; res[i] = hdf[i] - fl; isum += hdi[i];
    }
    int diff = 512 - isum;
    bool used[6] = {false, false, false, false, false, false};
    if (diff > 0) {
      for (int t = 0; t < diff; ++t) {
        int best = -1; float bv = -1e30f;
        for (int i = 0; i < 6; ++i) if (!used[i] && res[i] > bv) { bv = res[i]; best = i; }
        used[best] = true; hdi[best] += 1;
      }
    } else if (diff < 0) {
      for (int t = 0; t < -diff; ++t) {
        int best = -1; float bv = 1e30f;
        for (int i = 0; i < 6; ++i) if (!used[i] && res[i] < bv) { bv = res[i]; best = i; }
        used[best] = true; hdi[best] -= 1;
      }
    }
    { int st = 0, ast = 0;
      for (int i = 0; i < 6; ++i) {
        sh_starts[i] = st; sh_astarts[i] = ast;
        hdr[i] = hdi[i]; hdr[8 + i] = st; hdr[16 + i] = ast;
        st += hdi[i]; ast += (hdi[i] + 7) & ~7;
      }
      sh_starts[6] = st; sh_starts[7] = st;
    }
    // LPT: 24 (h,b) sets, 64 blocks each, 8 XCD bins cap 192
    int csth[6];
    for (int i = 0; i < 6; ++i) {
      int ncl = (hdi[i] + 31) / 32;
      int ntl = (hdi[i] + 15) / 16;
      csth[i] = 4 * ncl + 2 * ntl + 8;
    }
    int ord[6] = {0, 1, 2, 3, 4, 5};
    for (int a = 0; a < 6; ++a)
      for (int c = a + 1; c < 6; ++c)
        if (csth[ord[c]] > csth[ord[a]]) { int t = ord[a]; ord[a] = ord[c]; ord[c] = t; }
    int binload[8], bincnt[8];
    for (int x = 0; x < 8; ++x) { binload[x] = 0; bincnt[x] = 0; }
    int na = 0;
    for (int a = 0; a < 6; ++a) {
      const int hh = ord[a];
      for (int bb = 0; bb < 4; ++bb) {
        int best = -1;
        for (int x = 0; x < 8; ++x)
          if (bincnt[x] + 64 <= 192 && (best < 0 || binload[x] < binload[best])) best = x;
        if (best < 0) best = 0;
        sh_ax[na] = best; sh_apos[na] = bincnt[best];
        sh_ah[na] = hh; sh_ab[na] = bb; ++na;
        bincnt[best] += 64;
        binload[best] += csth[hh];
      }
    }
    // loss
    float dv = sumh - 512.0f;
    float floss = dv * dv;
    float rsum = 0.f;
    for (int i = 0; i < 6; ++i) rsum += fmaxf(8.0f - hdf[i], 0.0f);
    floss += rsum / 6.0f;
    float il = 0.f;
    for (int i = 0; i < 6; ++i) { float dd = hdf[i] - (float)hdi[i]; il += dd * dd; }
    il /= 6.0f;
    loss_out[0] = floss + 0.5f * il;
  }
  __syncthreads();

  for (int col = tid; col < 512; col += 64) {
    int hh = 5;
    for (int i = 0; i < 5; ++i) if (col < sh_starts[i + 1]) { hh = i; break; }
    int qc = sh_astarts[hh] + (col - sh_starts[hh]);
    cmap[col] = qc;
    cmap[512 + col] = QKSTRIDE + qc;
    cmap[1024 + col] = 4096 + col;
    cmap[1536 + col] = hh;
  }
  for (int e = tid; e < 1536; e += 64) sched[e] = -1;
  __syncthreads();
  for (int e = tid; e < 24 * 64; e += 64) {
    const int a = e >> 6, qi = e & 63;
    sched[sh_ax[a] + 8 * (sh_apos[a] + qi)] = sh_ah[a] | (sh_ab[a] << 4) | (qi << 8);
  }
}

// ---------------- fused converters: blocks [0,4096) conv query->bf16; [4096,4480) weight transposes ----------------
__global__ void conv_fused_kernel(const float* __restrict__ x, unsigned short* __restrict__ y,
                                  const float* __restrict__ Wqkv, const float* __restrict__ Wout,
                                  unsigned short* __restrict__ wqkvT, unsigned short* __restrict__ woutT) {
  __shared__ float tile[64][65];
  const int blk = blockIdx.x;
  const int t = threadIdx.x;
  if (blk < 4096) {
    const int i = blk * 256 + t;          // 4096*256 == 8192*512/4 exactly
    float4 v = reinterpret_cast<const float4*>(x)[i];
    union { unsigned short u[4]; uint2 q; } o;
    o.u[0] = f2bf(v.x); o.u[1] = f2bf(v.y); o.u[2] = f2bf(v.z); o.u[3] = f2bf(v.w);
    reinterpret_cast<uint2*>(y)[i] = o.q;
    return;
  }
  const int wb = blk - 4096;              // 0..383
  const int kx = wb & 7;
  const int rest = wb >> 3;               // 0..47
  const int ny = rest % 24, mz = rest / 24;
  if (mz && ny >= 8) return;
  const int N = mz ? 512 : 1536;
  const float* W = mz ? Wout : Wqkv;
  unsigned short* WT = mz ? woutT : wqkvT;
  const int k0 = kx * 64, n0 = ny * 64;
  {
    const int c = (t & 15) * 4;
#pragma unroll
    for (int rp = 0; rp < 4; ++rp) {
      const int r = rp * 16 + (t >> 4);
      float4 v = *reinterpret_cast<const float4*>(&W[(size_t)(k0 + r) * N + n0 + c]);
      tile[r][c] = v.x; tile[r][c + 1] = v.y; tile[r][c + 2] = v.z; tile[r][c + 3] = v.w;
    }
  }
  __syncthreads();
  {
    const int n = t >> 2, kc = (t & 3) * 16;
    unsigned short outv[16];
#pragma unroll
    for (int j = 0; j < 16; ++j) outv[j] = f2bf(tile[kc + j][n]);
    unsigned short* dst = &WT[(size_t)(n0 + n) * 512 + k0 + kc];
    *reinterpret_cast<u16x8*>(dst) = *reinterpret_cast<u16x8*>(&outv[0]);
    *reinterpret_cast<u16x8*>(dst + 8) = *reinterpret_cast<u16x8*>(&outv[8]);
  }
}

// ---------------- GEMM: C[M][N] = A[M][K](bf16) @ Bt[N][K]^T + bias ----------------
// MODE 0: f32 out. MODE 1: bf16 scatter; Q/K via cmap to qkpad, V written TRANSPOSED
// into Vt (packed 4x bf16 per store: per-thread rows are 4 consecutive t).
template<int MODE>
__global__ __launch_bounds__(256, 2) void gemm_bt(
    const unsigned short* __restrict__ A,
    const unsigned short* __restrict__ Bt,
    const float* __restrict__ bias,
    float* __restrict__ Cf,
    unsigned short* __restrict__ qkpad,
    unsigned short* __restrict__ VtOut,
    const int* __restrict__ cmap,
    int N, int K)
{
  __shared__ unsigned short As[128 * 32];
  __shared__ unsigned short Bs[128 * 32];
  const int tid = threadIdx.x;
  const int wave = tid >> 6, lane = tid & 63;
  const int lrow = lane & 15, lgrp = lane >> 4;
  const int wm = wave >> 1, wn = wave & 1;
  const int brow = blockIdx.y * 128;
  const int bcol = blockIdx.x * 128;

  f32x4 acc[4][4];
#pragma unroll
  for (int m = 0; m < 4; ++m)
#pragma unroll
    for (int n = 0; n < 4; ++n) acc[m][n] = (f32x4){0.f, 0.f, 0.f, 0.f};

  const int sig0 = wave * 128 + lane;
  for (int kb = 0; kb < K; kb += 32) {
    __syncthreads();
#pragma unroll
    for (int it = 0; it < 2; ++it) {
      const int sigma = sig0 + it * 64;
      const int r = sigma >> 2, sp = sigma & 3;
      const int sl = sp ^ ((r >> 1) & 3);
      gload_lds16(&A[(size_t)(brow + r) * K + kb + sl * 8], &As[sigma * 8]);
    }
#pragma unroll
    for (int it = 0; it < 2; ++it) {
      const int sigma = sig0 + it * 64;
      const int r = sigma >> 2, sp = sigma & 3;
      const int sl = sp ^ ((r >> 1) & 3);
      gload_lds16(&Bt[(size_t)(bcol + r) * K + kb + sl * 8], &Bs[sigma * 8]);
    }
    __syncthreads();
    const int sub = (lgrp ^ ((lrow >> 1) & 3)) * 8;
    bf16x8 aF[4], bF[4];
#pragma unroll
    for (int m = 0; m < 4; ++m)
      aF[m] = *reinterpret_cast<const bf16x8*>(&As[(wm * 64 + m * 16 + lrow) * 32 + sub]);
#pragma unroll
    for (int n = 0; n < 4; ++n)
      bF[n] = *reinterpret_cast<const bf16x8*>(&Bs[(wn * 64 + n * 16 + lrow) * 32 + sub]);
#pragma unroll
    for (int m = 0; m < 4; ++m)
#pragma unroll
      for (int n = 0; n < 4; ++n)
        acc[m][n] = __builtin_amdgcn_mfma_f32_16x16x32_bf16(aF[m], bF[n], acc[m][n], 0, 0, 0);
  }

#pragma unroll
  for (int n = 0; n < 4; ++n) {
    const int col = bcol + wn * 64 + n * 16 + lrow;
    const float bv = bias[col];
    int mc = 0;
    if (MODE == 1) mc = cmap[col];
#pragma unroll
    for (int m = 0; m < 4; ++m) {
      if (MODE == 0) {
#pragma unroll
        for (int r = 0; r < 4; ++r) {
          const int row = brow + wm * 64 + m * 16 + lgrp * 4 + r;
          Cf[(size_t)row * N + col] = acc[m][n][r] + bv;
        }
      } else if (mc < 4096) {
#pragma unroll
        for (int r = 0; r < 4; ++r) {
          const int row = brow + wm * 64 + m * 16 + lgrp * 4 + r;
          qkpad[(size_t)row * QKROW + mc] = f2bf(acc[m][n][r] + bv);
        }
      } else {
        // V: transpose on the fly. Rows are 4 consecutive t -> one 8B packed store.
        const int t0g = brow + wm * 64 + m * 16 + lgrp * 4;
        const int b = t0g >> 11, t0 = t0g & 2047;
        uint2 w;
        w.x = pack2bf(acc[m][n][0] + bv, acc[m][n][1] + bv);
        w.y = pack2bf(acc[m][n][2] + bv, acc[m][n][3] + bv);
        *reinterpret_cast<uint2*>(&VtOut[(size_t)(b * VTPAD + (mc - 4096)) * 2048 + t0]) = w;
      }
    }
  }
}

// ---------------- split-K flash attention (R17 body: V batch-0 hoisted for NC<=6) ----------------
template<int NC>
static __device__ __forceinline__ void attn_body(
    const unsigned short* __restrict__ qkpad,
    const unsigned short* __restrict__ Vt,
    unsigned short* __restrict__ Op,
    float2* __restrict__ mlArr,
    int b, int q0, int d, int start, int astart, int kh, int mlBase,
    unsigned char* KsB, unsigned int* PlW,
    int wave, int lane)
{
  constexpr int S = (4 * NC + 7) & ~7;
  constexpr int NT2 = 2 * NC;
  constexpr int NB0 = (NT2 < 8) ? NT2 : 8;
  constexpr bool HOIST = (NC <= 6);
  constexpr int KI = S / 8;
  constexpr int KTILE = 32 * S * 16;
  const int ntiles = (d + 15) >> 4;
  const int lrow = lane & 15, lgrp = lane >> 4;
  const float scale = 1.0f / sqrtf((float)d);

  bf16x8 qf[NC];
  {
    const unsigned short* qp = qkpad + (size_t)(b * 2048 + q0 + lrow) * QKROW + astart + lgrp * 8;
#pragma unroll
    for (int dc = 0; dc < NC; ++dc) {
      bf16x8 v = *reinterpret_cast<const bf16x8*>(qp + dc * 32);
#pragma unroll
      for (int j = 0; j < 8; ++j)
        if (dc * 32 + lgrp * 8 + j >= d) v[j] = (__bf16)0.0f;
      qf[dc] = v;
    }
  }

  const unsigned short* kPtr[KI];
  int kDstB[KI];
#pragma unroll
  for (int j = 0; j < KI; ++j) {
    const int g = (wave * KI + j) * 64 + lane;
    const int r = g / S, pp = g - r * S;
    const int sp = pp ^ (r & 7);
    kPtr[j] = qkpad + (size_t)(b * 2048 + kh * 1024 + r) * QKROW + QKSTRIDE + astart + sp * 8;
    kDstB[j] = g * 16;
  }

  const unsigned short* vRow = Vt + (size_t)(b * VTPAD + start + lrow) * 2048 + kh * 1024 + lgrp * 8;

  f32x4 acc[NT2];
#pragma unroll
  for (int t = 0; t < NT2; ++t) acc[t] = (f32x4){0.f, 0.f, 0.f, 0.f};
  float m_run = -1e30f, l_run = 0.f;

#pragma unroll
  for (int j = 0; j < KI; ++j) gload_lds16(kPtr[j], KsB + kDstB[j]);
#pragma unroll
  for (int j = 0; j < KI; ++j) kPtr[j] += 32 * QKROW;
  __syncthreads();

  for (int i = 0; i < 32; ++i) {
    const int kt = i << 5;
    const int cur = i & 1;
    if (i < 31) {
      unsigned char* kd = KsB + (cur ^ 1) * KTILE;
#pragma unroll
      for (int j = 0; j < KI; ++j) gload_lds16(kPtr[j], kd + kDstB[j]);
#pragma unroll
      for (int j = 0; j < KI; ++j) kPtr[j] += 32 * QKROW;
    }

    // ---- V batch-0 hoist (NC<=6): L2 latency lands under QK + softmax ----
    bf16x8 vf0[NB0];
    if constexpr (HOIST) {
#pragma unroll
      for (int j = 0; j < NB0; ++j)
        if (j < ntiles)
          vf0[j] = *reinterpret_cast<const bf16x8*>(vRow + (size_t)j * 32768 + kt);
    }

    f32x4 s4[2];
    s4[0] = (f32x4){0.f, 0.f, 0.f, 0.f};
    s4[1] = (f32x4){0.f, 0.f, 0.f, 0.f};
    const unsigned char* kB = KsB + cur * KTILE;
    const int swz = lrow & 7;
    __builtin_amdgcn_s_setprio(1);
#pragma unroll
    for (int dc = 0; dc < NC; ++dc) {
#pragma unroll
      for (int t = 0; t < 2; ++t) {
        const bf16x8 kf = *reinterpret_cast<const bf16x8*>(
            kB + (t * 16 + lrow) * (S * 16) + (((dc * 4 + lgrp) ^ swz) * 16));
        s4[t] = __builtin_amdgcn_mfma_f32_16x16x32_bf16(kf, qf[dc], s4[t], 0, 0, 0);
      }
    }
    __builtin_amdgcn_s_setprio(0);

    float ps[8];
#pragma unroll
    for (int t = 0; t < 2; ++t)
#pragma unroll
      for (int r = 0; r < 4; ++r) ps[t * 4 + r] = s4[t][r] * scale;
    float pm = ps[0];
#pragma unroll
    for (int z = 1; z < 8; ++z) pm = fmaxf(pm, ps[z]);
    pm = fmaxf(pm, __shfl_xor(pm, 16));
    pm = fmaxf(pm, __shfl_xor(pm, 32));
    if (__any(pm > m_run + 8.0f)) {
      const float mn = fmaxf(m_run, pm);
      const float alpha = __expf(m_run - mn);
      m_run = mn; l_run *= alpha;
      float al4[4];
#pragma unroll
      for (int r = 0; r < 4; ++r) al4[r] = __shfl(alpha, lgrp * 4 + r);
#pragma unroll
      for (int t = 0; t < NT2; ++t) {
        if (t < ntiles) {
#pragma unroll
          for (int r = 0; r < 4; ++r) acc[t][r] *= al4[r];
        }
      }
    }
    float sum = 0.f;
#pragma unroll
    for (int z = 0; z < 8; ++z) { ps[z] = __expf(ps[z] - m_run); sum += ps[z]; }
    sum += __shfl_xor(sum, 16);
    sum += __shfl_xor(sum, 32);
    l_run += sum;

#pragma unroll
    for (int t = 0; t < 2; ++t) {
      uint2 w;
      w.x = pack2bf(ps[t * 4 + 0], ps[t * 4 + 1]);
      w.y = pack2bf(ps[t * 4 + 2], ps[t * 4 + 3]);
      *reinterpret_cast<uint2*>(PlW + lrow * 20 + 8 * t + 2 * lgrp) = w;
    }
    asm volatile("s_waitcnt lgkmcnt(0)" ::: "memory");
    __builtin_amdgcn_sched_barrier(0);
    const bf16x8 pa = *reinterpret_cast<const bf16x8*>(PlW + lrow * 20 + 4 * lgrp);

    if constexpr (HOIST) {
      __builtin_amdgcn_s_setprio(1);
#pragma unroll
      for (int j = 0; j < NB0; ++j)
        if (j < ntiles)
          acc[j] = __builtin_amdgcn_mfma_f32_16x16x32_bf16(pa, vf0[j], acc[j], 0, 0, 0);
      __builtin_amdgcn_s_setprio(0);
      if constexpr (NT2 > 8) {
        bf16x8 vf1[NT2 - 8];
#pragma unroll
        for (int j = 0; j < NT2 - 8; ++j) {
          const int t = 8 + j;
          if (t < ntiles)
            vf1[j] = *reinterpret_cast<const bf16x8*>(vRow + (size_t)t * 32768 + kt);
        }
        __builtin_amdgcn_s_setprio(1);
#pragma unroll
        for (int j = 0; j < NT2 - 8; ++j) {
          const int t = 8 + j;
          if (t < ntiles)
            acc[t] = __builtin_amdgcn_mfma_f32_16x16x32_bf16(pa, vf1[j], acc[t], 0, 0, 0);
        }
        __builtin_amdgcn_s_setprio(0);
      }
    } else {
#pragma unroll
      for (int t0 = 0; t0 < NT2; t0 += 8) {
        bf16x8 vf[8];
#pragma unroll
        for (int j = 0; j < 8; ++j) {
          const int t = t0 + j;
          if (t < NT2 && t < ntiles)
            vf[j] = *reinterpret_cast<const bf16x8*>(vRow + (size_t)t * 32768 + kt);
        }
        __builtin_amdgcn_s_setprio(1);
#pragma unroll
        for (int j = 0; j < 8; ++j) {
          const int t = t0 + j;
          if (t < NT2 && t < ntiles)
            acc[t] = __builtin_amdgcn_mfma_f32_16x16x32_bf16(pa, vf[j], acc[t], 0, 0, 0);
        }
        __builtin_amdgcn_s_setprio(0);
      }
    }
    __syncthreads();
  }

  float invl[4];
#pragma unroll
  for (int r = 0; r < 4; ++r) invl[r] = 1.0f / __shfl(l_run, lgrp * 4 + r);
#pragma unroll
  for (int t = 0; t < NT2; ++t) {
    if (t < ntiles) {
      const int col = t * 16 + lrow;
      if (col < d) {
#pragma unroll
        for (int r = 0; r < 4; ++r) {
          Op[(size_t)(b * 2048 + q0 + lgrp * 4 + r) * 512 + start + col] =
              f2bf(acc[t][r] * invl[r]);
        }
      }
    }
  }
  if (lgrp == 0) mlArr[mlBase + lrow] = make_float2(m_run, l_run);
}

__global__ __launch_bounds__(256, 3) void attn_fused(
    const unsigned short* __restrict__ qkpad,
    const unsigned short* __restrict__ Vt,
    unsigned short* __restrict__ O0,
    unsigned short* __restrict__ O1,
    float2* __restrict__ mlArr,
    const int* __restrict__ hdr,
    const int* __restrict__ sched)
{
  __shared__ __align__(16) unsigned char KsB[32768];
  __shared__ unsigned int Pl[4][16 * 20];

  const int sv = sched[blockIdx.x];
  if (sv < 0) return;
  const int h = sv & 15, b = (sv >> 4) & 15;
  const int qi = (sv >> 8) & 63;
  const int qb = qi & 31, kh = qi >> 5;
  const int d = hdr[h];
  const int nc = (d + 31) >> 5;
  if (nc > 8) return;
  const int start = hdr[8 + h];
  const int astart = hdr[16 + h];
  const int wave = threadIdx.x >> 6, lane = threadIdx.x & 63;
  const int q0 = qb * 64 + wave * 16;
  unsigned short* Op = kh ? O1 : O0;
  const int mlBase = (kh * 24 + h * 4 + b) * 2048 + q0;

  unsigned int* PlW = &Pl[wave][0];
  switch (nc) {
    case 1: attn_body<1>(qkpad, Vt, Op, mlArr, b, q0, d, start, astart, kh, mlBase, KsB, PlW, wave, lane); break;
    case 2: attn_body<2>(qkpad, Vt, Op, mlArr, b, q0, d, start, astart, kh, mlBase, KsB, PlW, wave, lane); break;
    case 3: attn_body<3>(qkpad, Vt, Op, mlArr, b, q0, d, start, astart, kh, mlBase, KsB, PlW, wave, lane); break;
    case 4: attn_body<4>(qkpad, Vt, Op, mlArr, b, q0, d, start, astart, kh, mlBase, KsB, PlW, wave, lane); break;
    case 5: attn_body<5>(qkpad, Vt, Op, mlArr, b, q0, d, start, astart, kh, mlBase, KsB, PlW, wave, lane); break;
    case 6: attn_body<6>(qkpad, Vt, Op, mlArr, b, q0, d, start, astart, kh, mlBase, KsB, PlW, wave, lane); break;
    case 7: attn_body<7>(qkpad, Vt, Op, mlArr, b, q0, d, start, astart, kh, mlBase, KsB, PlW, wave, lane); break;
    case 8: attn_body<8>(qkpad, Vt, Op, mlArr, b, q0, d, start, astart, kh, mlBase, KsB, PlW, wave, lane); break;
    default: break;
  }
}

// ---------------- merge v2: per-(b,h) blocks; ratio computed once per row ----------------
__global__ __launch_bounds__(256) void merge_kernel(
    const unsigned short* __restrict__ O0,
    const unsigned short* __restrict__ O1,
    const float2* __restrict__ mlArr,
    unsigned short* __restrict__ attnC,
    const int* __restrict__ hdr)
{
  const int sh = blockIdx.y;                 // 0..23
  const int h = sh >> 2, b = sh & 3;
  const int d = hdr[h];
  if (((d + 31) >> 5) > 8) return;
  const int start = hdr[8 + h];
  const int q = blockIdx.x * 32 + (threadIdx.x >> 3);
  const int cg = threadIdx.x & 7;
  const float2 A = mlArr[(h * 4 + b) * 2048 + q];
  const float2 B = mlArr[(24 + h * 4 + b) * 2048 + q];
  const float M = fmaxf(A.x, B.x);
  const float a1 = __expf(A.x - M) * A.y;
  const float a2 = __expf(B.x - M) * B.y;
  const float inv = 1.0f / (a1 + a2);
  const float r1 = a1 * inv, r2 = a2 * inv;
  const size_t base = (size_t)(b * 2048 + q) * 512 + start;
  for (int c = cg; c < d; c += 8)
    attnC[base + c] = f2bf(r1 * bf2f(O0[base + c]) + r2 * bf2f(O1[base + c]));
}

// ---------------- launch ----------------
extern "C" void kernel_launch(void* const* d_in, const int* in_sizes, int n_in,
                              void* d_out, int out_size, void* d_ws, size_t ws_size,
                              hipStream_t stream) {
  const float* query  = (const float*)d_in[0];
  const float* logits = (const float*)d_in[1];
  const float* w_qkv  = (const float*)d_in[2];
  const float* b_qkv  = (const float*)d_in[3];
  const float* w_out  = (const float*)d_in[4];
  const float* b_out  = (const float*)d_in[5];
  float* out = (float*)d_out;

  char* p = (char*)d_ws;
  size_t off = 0;
  auto alloc = [&](size_t bytes) {
    void* r = p + off; off += (bytes + 255) & ~(size_t)255; return r;
  };
  int* hdr              = (int*)alloc(1024);
  int* cmap             = (int*)alloc(2048 * 4);
  int* sched            = (int*)alloc(1536 * 4);
  unsigned short* qbf   = (unsigned short*)alloc((size_t)8192 * 512 * 2);   // reused as O0
  unsigned short* wqkvT = (unsigned short*)alloc((size_t)1536 * 512 * 2);
  unsigned short* woutT = (unsigned short*)alloc((size_t)512 * 512 * 2);
  unsigned short* qkpad = (unsigned short*)alloc((size_t)8192 * QKROW * 2 + 4096);
  unsigned short* vbuf  = (unsigned short*)alloc((size_t)8192 * 512 * 2);   // reused as O1
  unsigned short* Vt    = (unsigned short*)alloc((size_t)4 * VTPAD * 2048 * 2 + 4096);
  unsigned short* attnC = (unsigned short*)alloc((size_t)8192 * 512 * 2);
  float2* mlArr         = (float2*)alloc((size_t)2 * 24 * 2048 * 8);
  (void)ws_size; (void)in_sizes; (void)n_in; (void)out_size;

  prep_kernel<<<1, 64, 0, stream>>>(logits, hdr, cmap, sched, out + 4194304);
  conv_fused_kernel<<<4480, 256, 0, stream>>>(query, qbf, w_qkv, w_out, wqkvT, woutT);
  gemm_bt<1><<<dim3(12, 64), 256, 0, stream>>>(qbf, wqkvT, b_qkv, nullptr, qkpad, Vt, cmap, 1536, 512);
  // qbf/vbuf dead from here -> reuse as split-K partial buffers O0/O1 (transV fused into gemm)
  attn_fused<<<dim3(1536, 1, 1), 256, 0, stream>>>(qkpad, Vt, qbf, vbuf, mlArr, hdr, sched);
  merge_kernel<<<dim3(64, 24), 256, 0, stream>>>(qbf, vbuf, mlArr, attnC, hdr);
  gemm_bt<0><<<dim3(4, 64), 256, 0, stream>>>(attnC, woutT, b_out, out, nullptr, nullptr, nullptr, 512, 512);
}